// Round 3
// baseline (1111.660 us; speedup 1.0000x reference)
//
#include <hip/hip_runtime.h>
#include <hip/hip_bf16.h>

#define C_ 256
#define L_ 16384
#define CL_ (C_*L_)

typedef unsigned int u32;
typedef unsigned short u16;
typedef __bf16 bf16_t;
typedef bf16_t bf16x8 __attribute__((ext_vector_type(8)));
typedef float f32x4 __attribute__((ext_vector_type(4)));

__device__ __forceinline__ float bf2f(u16 v){ return __builtin_bit_cast(float, ((u32)v)<<16); }
__device__ __forceinline__ u16 f2bf(float f){
  u32 u = __builtin_bit_cast(u32, f);
  u32 r = u + 0x7FFFu + ((u>>16)&1u);
  return (u16)(r>>16);
}

// ---------------- weight transpose+downcast kernel ----------------
// fp32 W(R x Cc) row-major -> bf16 W^T(Cc x R)
__global__ void wtrans_kernel(const float* __restrict__ qkvw, const float* __restrict__ projw,
                              const float* __restrict__ f1w, const float* __restrict__ f2w,
                              u16* __restrict__ qkvT, u16* __restrict__ projT,
                              u16* __restrict__ f1T, u16* __restrict__ f2T)
{
  __shared__ u16 tile[32][33];
  int id = blockIdx.x;
  const float* src; u16* dst; int R, Cc;
  if (id < 192){ src = qkvw; dst = qkvT; R = 256; Cc = 768; }
  else if (id < 192+64){ id -= 192; src = projw; dst = projT; R = 256; Cc = 256; }
  else if (id < 192+64+256){ id -= 192+64; src = f1w; dst = f1T; R = 256; Cc = 1024; }
  else { id -= 192+64+256; src = f2w; dst = f2T; R = 1024; Cc = 256; }
  int ctiles = Cc >> 5;
  int r0 = (id / ctiles) << 5, c0 = (id % ctiles) << 5;
  int tx = threadIdx.x & 31, ty = threadIdx.x >> 5;
  #pragma unroll
  for (int i = 0; i < 4; ++i){
    int r = ty + 8*i;
    tile[r][tx] = f2bf(src[(size_t)(r0 + r)*Cc + c0 + tx]);
  }
  __syncthreads();
  #pragma unroll
  for (int i = 0; i < 4; ++i){
    int c = ty + 8*i;
    dst[(size_t)(c0 + c)*R + r0 + tx] = tile[tx][c];
  }
}

// ---------------- GEMM helpers ----------------
// Weight stage (K-step 64): chunk (ks, ntile, lane)*16B holds
// WT[ntile*16 + (lane&15)][koff + ks*32 + (lane>>4)*8 .. +8)
__device__ __forceinline__ void stageW(const u16* __restrict__ base, int stride, int koff,
                                       u16* Wl, int tid)
{
  #pragma unroll
  for (int ii = 0; ii < 4; ++ii){
    int id = tid + ii*512;
    int n = id >> 3, gg = id & 7;
    uint4 d = *(const uint4*)(base + (size_t)n*stride + koff + gg*8);
    int ks = gg >> 2, g = gg & 3;
    *(uint4*)((char*)Wl + ((ks*16 + (n>>4))*64 + ((g<<4)|(n&15)))*16) = d;
  }
}

// A tile layout: byte = t*512 + ((2k) ^ ((t&7)<<4)), t in [0,64), k in [0,256)
__device__ __forceinline__ void mfma_block(const u16* Abase, const u16* Wl, int k0, int ntb,
                                           int l, f32x4 acc[4][2])
{
  #pragma unroll
  for (int ks = 0; ks < 2; ++ks){
    int kk = k0 + ks*32;
    bf16x8 a[4];
    #pragma unroll
    for (int m = 0; m < 4; ++m){
      int t = m*16 + (l & 15);
      int off = t*512 + ((2*(kk + ((l>>4)<<3))) ^ ((t&7)<<4));
      a[m] = *(const bf16x8*)((const char*)Abase + off);
    }
    #pragma unroll
    for (int n2 = 0; n2 < 2; ++n2){
      bf16x8 bb = *(const bf16x8*)((const char*)Wl + ((ks*16 + ntb + n2)*64 + l)*16);
      #pragma unroll
      for (int m = 0; m < 4; ++m)
        acc[m][n2] = __builtin_amdgcn_mfma_f32_16x16x32_bf16(a[m], bb, acc[m][n2], 0, 0, 0);
    }
  }
}

// full 64x256 @ 256xN-slice GEMM accumulation (K=256)
__device__ __forceinline__ void gemm_acc(const u16* Abase, const u16* __restrict__ Wsrc,
                                         int wstride, int kbase, u16* Wl,
                                         int tid, int ntb, int l, f32x4 acc[4][2])
{
  #pragma unroll 1
  for (int k0 = 0; k0 < 256; k0 += 64){
    __syncthreads();
    stageW(Wsrc, wstride, kbase + k0, Wl, tid);
    __syncthreads();
    mfma_block(Abase, Wl, k0, ntb, l, acc);
  }
}

// ---------------- fully fused block kernel ----------------
// block = 64 tokens (original positions (blk*64+4+t) mod L), 512 threads, 128 KiB LDS
__launch_bounds__(512, 1)
__global__ void swin_fused_kernel(const float* __restrict__ x,
                                  const float* __restrict__ n1w, const float* __restrict__ n1b,
                                  const float* __restrict__ n2w, const float* __restrict__ n2b,
                                  const u16* __restrict__ qkvT, const u16* __restrict__ projT,
                                  const float* __restrict__ projb,
                                  const u16* __restrict__ f1T, const float* __restrict__ f1b,
                                  const u16* __restrict__ f2T, const float* __restrict__ f2b,
                                  float* __restrict__ out)
{
  __shared__ u16 smem[65536];            // 128 KiB exactly
  u16* Aln = smem;                       // 0..32K   : LN1 A-tile -> raw dump -> H chunk -> fp32 out stage
  u16* Qb  = smem + 16384;               // 32..64K  : Q -> attn-out A-tile -> LN2 A-tile
  u16* Kb  = smem + 32768;               // 64..96K  : K -> V -> xt1 tile (linear)
  u16* Wl  = smem + 49152;               // 96..128K : LN1 stats scratch / weight stage

  const int tid = threadIdx.x;
  const int w = tid >> 6;
  const int l = tid & 63;
  const int bb = blockIdx.x >> 8;
  const int blkl = blockIdx.x & 255;
  const int l0 = blkl*64 + 4;
  const float* xb = x + (size_t)bb*CL_;
  const int ntb = w*2;

  // ---- phase 1: load x (transposing), LN1 ----
  const int q4 = tid & 15, cb = tid >> 4;
  int lq = l0 + 4*q4; if (lq >= L_) lq -= L_;
  float4 rawp[8];
  float s1[4] = {0.f,0.f,0.f,0.f};
  float s2[4] = {0.f,0.f,0.f,0.f};
  #pragma unroll
  for (int it = 0; it < 8; ++it){
    int c = cb + 32*it;
    float4 d = *(const float4*)(xb + (size_t)c*L_ + lq);
    rawp[it] = d;
    s1[0]+=d.x; s2[0]+=d.x*d.x;  s1[1]+=d.y; s2[1]+=d.y*d.y;
    s1[2]+=d.z; s2[2]+=d.z*d.z;  s1[3]+=d.w; s2[3]+=d.w*d.w;
  }
  #pragma unroll
  for (int off = 16; off < 64; off <<= 1){
    #pragma unroll
    for (int jj = 0; jj < 4; ++jj){
      s1[jj] += __shfl_xor(s1[jj], off);
      s2[jj] += __shfl_xor(s2[jj], off);
    }
  }
  float* red = (float*)Wl;          // [2][8][64] partials
  float* stats = red + 1024;        // [64][2]
  if (l < 16){
    #pragma unroll
    for (int jj = 0; jj < 4; ++jj){
      red[w*64 + 4*l + jj] = s1[jj];
      red[512 + w*64 + 4*l + jj] = s2[jj];
    }
  }
  __syncthreads();
  if (tid < 64){
    float a = 0.f, b2 = 0.f;
    #pragma unroll
    for (int ww = 0; ww < 8; ++ww){ a += red[ww*64 + tid]; b2 += red[512 + ww*64 + tid]; }
    float mu = a * (1.f/256.f);
    float var = fmaxf(b2 * (1.f/256.f) - mu*mu, 0.f);
    stats[2*tid] = mu;
    stats[2*tid+1] = rsqrtf(var + 1e-5f);
  }
  __syncthreads();
  #pragma unroll
  for (int it = 0; it < 8; ++it){
    int c = cb + 32*it;
    float wc = n1w[c], bc = n1b[c];
    float f[4] = {rawp[it].x, rawp[it].y, rawp[it].z, rawp[it].w};
    #pragma unroll
    for (int jj = 0; jj < 4; ++jj){
      int t = 4*q4 + jj;
      float a = (f[jj] - stats[2*t]) * stats[2*t+1] * wc + bc;
      *(u16*)((char*)Aln + t*512 + ((2*c) ^ ((t&7)<<4))) = f2bf(a);
    }
  }

  // ---- Q GEMM ----
  {
    f32x4 acc[4][2];
    #pragma unroll
    for (int m = 0; m < 4; ++m){ acc[m][0] = (f32x4){0,0,0,0}; acc[m][1] = (f32x4){0,0,0,0}; }
    gemm_acc(Aln, qkvT, 256, 0, Wl, tid, ntb, l, acc);
    #pragma unroll
    for (int m = 0; m < 4; ++m)
      #pragma unroll
      for (int n2 = 0; n2 < 2; ++n2)
        #pragma unroll
        for (int jj = 0; jj < 4; ++jj){
          int t = m*16 + ((l>>4)<<2) + jj;
          int c = (w<<5) + (n2<<4) + (l&15);
          *(u16*)((char*)Qb + t*512 + ((2*c) ^ ((t&7)<<4))) = f2bf(acc[m][n2][jj]);
        }
  }
  // ---- K GEMM ----
  {
    f32x4 acc[4][2];
    #pragma unroll
    for (int m = 0; m < 4; ++m){ acc[m][0] = (f32x4){0,0,0,0}; acc[m][1] = (f32x4){0,0,0,0}; }
    gemm_acc(Aln, qkvT + 65536, 256, 0, Wl, tid, ntb, l, acc);
    #pragma unroll
    for (int m = 0; m < 4; ++m)
      #pragma unroll
      for (int n2 = 0; n2 < 2; ++n2)
        #pragma unroll
        for (int jj = 0; jj < 4; ++jj){
          int t = m*16 + ((l>>4)<<2) + jj;
          int c = (w<<5) + (n2<<4) + (l&15);
          *(u16*)((char*)Kb + t*512 + ((2*c) ^ ((t&7)<<4))) = f2bf(acc[m][n2][jj]);
        }
  }
  __syncthreads();

  // ---- scores + softmax (probs kept in registers across V GEMM) ----
  float pr[8];
  {
    const int h = (tid >> 3) & 7, r = tid & 7;
    const int t = w*8 + r;
    float qf[32]; u32 kr[16];
    #pragma unroll
    for (int g = 0; g < 4; ++g){
      int off = t*512 + ((h*64 + 16*g) ^ ((t&7)<<4));
      uint4 dq = *(const uint4*)((char*)Qb + off);
      uint4 dk = *(const uint4*)((char*)Kb + off);
      qf[g*8+0] = bf2f((u16)dq.x); qf[g*8+1] = bf2f((u16)(dq.x>>16));
      qf[g*8+2] = bf2f((u16)dq.y); qf[g*8+3] = bf2f((u16)(dq.y>>16));
      qf[g*8+4] = bf2f((u16)dq.z); qf[g*8+5] = bf2f((u16)(dq.z>>16));
      qf[g*8+6] = bf2f((u16)dq.w); qf[g*8+7] = bf2f((u16)(dq.w>>16));
      kr[g*4+0] = dk.x; kr[g*4+1] = dk.y; kr[g*4+2] = dk.z; kr[g*4+3] = dk.w;
    }
    float s[8];
    #pragma unroll
    for (int j = 0; j < 8; ++j){
      float dot = 0.f;
      #pragma unroll
      for (int reg = 0; reg < 16; ++reg){
        u32 kj = (u32)__shfl((int)kr[reg], j, 8);
        dot += qf[2*reg]   * bf2f((u16)kj);
        dot += qf[2*reg+1] * bf2f((u16)(kj>>16));
      }
      s[j] = dot * 0.17677669529663687f;
    }
    float mx = s[0];
    #pragma unroll
    for (int j = 1; j < 8; ++j) mx = fmaxf(mx, s[j]);
    float sum = 0.f;
    #pragma unroll
    for (int j = 0; j < 8; ++j){ pr[j] = __expf(s[j]-mx); sum += pr[j]; }
    float inv = 1.0f / sum;
    #pragma unroll
    for (int j = 0; j < 8; ++j) pr[j] *= inv;
  }

  // ---- V GEMM (A=Aln still live) -> overwrite Kb ----
  {
    f32x4 acc[4][2];
    #pragma unroll
    for (int m = 0; m < 4; ++m){ acc[m][0] = (f32x4){0,0,0,0}; acc[m][1] = (f32x4){0,0,0,0}; }
    gemm_acc(Aln, qkvT + 131072, 256, 0, Wl, tid, ntb, l, acc);
    #pragma unroll
    for (int m = 0; m < 4; ++m)
      #pragma unroll
      for (int n2 = 0; n2 < 2; ++n2)
        #pragma unroll
        for (int jj = 0; jj < 4; ++jj){
          int t = m*16 + ((l>>4)<<2) + jj;
          int c = (w<<5) + (n2<<4) + (l&15);
          *(u16*)((char*)Kb + t*512 + ((2*c) ^ ((t&7)<<4))) = f2bf(acc[m][n2][jj]);
        }
  }
  __syncthreads();

  // ---- raw x dump into Aln (linear [64][256], bf16) ----
  #pragma unroll
  for (int it = 0; it < 8; ++it){
    int c = cb + 32*it;
    float f[4] = {rawp[it].x, rawp[it].y, rawp[it].z, rawp[it].w};
    #pragma unroll
    for (int jj = 0; jj < 4; ++jj){
      int t = 4*q4 + jj;
      *(u16*)((char*)Aln + t*512 + 2*c) = f2bf(f[jj]);
    }
  }

  // ---- PV -> attn out into Qb (swizzled A-tile) ----
  {
    const int h = (tid >> 3) & 7, r = tid & 7;
    const int t = w*8 + r;
    u32 vr[16];
    #pragma unroll
    for (int g = 0; g < 4; ++g){
      int off = t*512 + ((h*64 + 16*g) ^ ((t&7)<<4));
      uint4 dv = *(const uint4*)((char*)Kb + off);
      vr[g*4+0] = dv.x; vr[g*4+1] = dv.y; vr[g*4+2] = dv.z; vr[g*4+3] = dv.w;
    }
    float of[32];
    #pragma unroll
    for (int d = 0; d < 32; ++d) of[d] = 0.f;
    #pragma unroll
    for (int j = 0; j < 8; ++j){
      float pj = pr[j];
      #pragma unroll
      for (int reg = 0; reg < 16; ++reg){
        u32 vj = (u32)__shfl((int)vr[reg], j, 8);
        of[2*reg]   += pj*bf2f((u16)vj);
        of[2*reg+1] += pj*bf2f((u16)(vj>>16));
      }
    }
    #pragma unroll
    for (int g = 0; g < 4; ++g){
      uint4 o;
      o.x = (u32)f2bf(of[g*8+0]) | ((u32)f2bf(of[g*8+1])<<16);
      o.y = (u32)f2bf(of[g*8+2]) | ((u32)f2bf(of[g*8+3])<<16);
      o.z = (u32)f2bf(of[g*8+4]) | ((u32)f2bf(of[g*8+5])<<16);
      o.w = (u32)f2bf(of[g*8+6]) | ((u32)f2bf(of[g*8+7])<<16);
      *(uint4*)((char*)Qb + t*512 + ((h*64 + 16*g) ^ ((t&7)<<4))) = o;
    }
  }

  // ---- proj GEMM (A=Qb) + bias + residual -> xt1 tile in Kb (linear, bf16) ----
  {
    f32x4 acc[4][2];
    #pragma unroll
    for (int m = 0; m < 4; ++m){ acc[m][0] = (f32x4){0,0,0,0}; acc[m][1] = (f32x4){0,0,0,0}; }
    gemm_acc(Qb, projT, 256, 0, Wl, tid, ntb, l, acc);
    #pragma unroll
    for (int m = 0; m < 4; ++m)
      #pragma unroll
      for (int n2 = 0; n2 < 2; ++n2)
        #pragma unroll
        for (int jj = 0; jj < 4; ++jj){
          int t = m*16 + ((l>>4)<<2) + jj;
          int c = (w<<5) + (n2<<4) + (l&15);
          float v = acc[m][n2][jj] + projb[c] + bf2f(*(const u16*)((char*)Aln + t*512 + 2*c));
          *(u16*)((char*)Kb + t*512 + 2*c) = f2bf(v);
        }
  }
  __syncthreads();

  // ---- LN2 (read Kb linear, write Qb swizzled A-tile) ----
  {
    float4 wv = *(const float4*)(n2w + 4*l);
    float4 bv = *(const float4*)(n2b + 4*l);
    float wf[4] = {wv.x, wv.y, wv.z, wv.w};
    float bfv[4] = {bv.x, bv.y, bv.z, bv.w};
    #pragma unroll 1
    for (int r = 0; r < 8; ++r){
      int t = w*8 + r;
      uint2 d = *(const uint2*)((char*)Kb + t*512 + 8*l);
      float f0 = bf2f((u16)d.x), f1 = bf2f((u16)(d.x>>16));
      float f2 = bf2f((u16)d.y), f3 = bf2f((u16)(d.y>>16));
      float ls1 = f0+f1+f2+f3;
      float ls2 = f0*f0+f1*f1+f2*f2+f3*f3;
      #pragma unroll
      for (int off = 1; off < 64; off <<= 1){
        ls1 += __shfl_xor(ls1, off);
        ls2 += __shfl_xor(ls2, off);
      }
      float mu = ls1 * (1.f/256.f);
      float var = fmaxf(ls2 * (1.f/256.f) - mu*mu, 0.f);
      float rs = rsqrtf(var + 1e-5f);
      uint2 pp;
      pp.x = (u32)f2bf((f0-mu)*rs*wf[0]+bfv[0]) | ((u32)f2bf((f1-mu)*rs*wf[1]+bfv[1])<<16);
      pp.y = (u32)f2bf((f2-mu)*rs*wf[2]+bfv[2]) | ((u32)f2bf((f3-mu)*rs*wf[3]+bfv[3])<<16);
      *(uint2*)((char*)Qb + t*512 + ((8*l) ^ ((t&7)<<4))) = pp;
    }
  }

  // ---- FF: 4 chunks of 256 hidden; H lives in Aln ----
  f32x4 acc2[4][2];
  #pragma unroll
  for (int m = 0; m < 4; ++m){ acc2[m][0] = (f32x4){0,0,0,0}; acc2[m][1] = (f32x4){0,0,0,0}; }
  #pragma unroll 1
  for (int c2 = 0; c2 < 4; ++c2){
    f32x4 acc1[4][2];
    #pragma unroll
    for (int m = 0; m < 4; ++m){ acc1[m][0] = (f32x4){0,0,0,0}; acc1[m][1] = (f32x4){0,0,0,0}; }
    gemm_acc(Qb, f1T + (size_t)c2*65536, 256, 0, Wl, tid, ntb, l, acc1);
    #pragma unroll
    for (int m = 0; m < 4; ++m)
      #pragma unroll
      for (int n2 = 0; n2 < 2; ++n2)
        #pragma unroll
        for (int jj = 0; jj < 4; ++jj){
          int t = m*16 + ((l>>4)<<2) + jj;
          int c = (w<<5) + (n2<<4) + (l&15);
          float xv = acc1[m][n2][jj] + f1b[c2*256 + c];
          float g = 0.5f*xv*(1.f + erff(xv*0.70710678118654752f));
          *(u16*)((char*)Aln + t*512 + ((2*c) ^ ((t&7)<<4))) = f2bf(g);
        }
    gemm_acc(Aln, f2T, 1024, c2*256, Wl, tid, ntb, l, acc2);
  }

  // ---- final epilogue: +f2b +residual(Kb), fp32 stage in Aln, 2 half-channel passes ----
  float* OutF = (float*)Aln;          // [128 rows][64 t] fp32, t XOR-swizzled
  float* ob = out + (size_t)bb*CL_;
  #pragma unroll
  for (int n2p = 0; n2p < 2; ++n2p){
    __syncthreads();                  // Aln free (all prior readers done)
    #pragma unroll
    for (int m = 0; m < 4; ++m)
      #pragma unroll
      for (int jj = 0; jj < 4; ++jj){
        int t = m*16 + ((l>>4)<<2) + jj;
        int c = (w<<5) + (n2p<<4) + (l&15);
        int row = (w<<4) + (l&15);
        float v = acc2[m][n2p][jj] + f2b[c] + bf2f(*(const u16*)((char*)Kb + t*512 + 2*c));
        OutF[row*64 + (t ^ ((row&7)<<3))] = v;
      }
    __syncthreads();
    #pragma unroll
    for (int ii = 0; ii < 4; ++ii){
      int id = tid + ii*512;
      int row = id >> 4, qd = id & 15;
      int cg = ((row>>4)<<5) + (n2p<<4) + (row&15);
      int lw = l0 + 4*qd; if (lw >= L_) lw -= L_;
      float4 vv = *(const float4*)(OutF + row*64 + ((4*qd) ^ ((row&7)<<3)));
      *(float4*)(ob + (size_t)cg*L_ + lw) = vv;
    }
  }
}

// ---------------- launch ----------------
extern "C" void kernel_launch(void* const* d_in, const int* in_sizes, int n_in,
                              void* d_out, int out_size, void* d_ws, size_t ws_size,
                              hipStream_t stream)
{
  const float* x     = (const float*)d_in[0];
  const float* n1w   = (const float*)d_in[1];
  const float* n1b   = (const float*)d_in[2];
  const float* n2w   = (const float*)d_in[3];
  const float* n2b   = (const float*)d_in[4];
  const float* qkvw  = (const float*)d_in[5];
  const float* projw = (const float*)d_in[6];
  const float* projb = (const float*)d_in[7];
  const float* f1w   = (const float*)d_in[8];
  const float* f1b   = (const float*)d_in[9];
  const float* f2w   = (const float*)d_in[10];
  const float* f2b   = (const float*)d_in[11];
  float* out = (float*)d_out;

  u16* ws    = (u16*)d_ws;
  u16* qkvT  = ws;                      // 768*256  = 196608
  u16* projT = qkvT + 196608;           // 256*256  = 65536
  u16* f1T   = projT + 65536;           // 1024*256 = 262144
  u16* f2T   = f1T + 262144;            // 256*1024 = 262144   (total 1.57 MB bf16)

  hipLaunchKernelGGL(wtrans_kernel, dim3(768), dim3(256), 0, stream,
                     qkvw, projw, f1w, f2w, qkvT, projT, f1T, f2T);
  hipLaunchKernelGGL(swin_fused_kernel, dim3(2048), dim3(512), 0, stream,
                     x, n1w, n1b, n2w, n2b, qkvT, projT, projb, f1T, f1b, f2T, f2b, out);
}

// Round 4
// 1052.490 us; speedup vs baseline: 1.0562x; 1.0562x over previous
//
#include <hip/hip_runtime.h>
#include <hip/hip_bf16.h>

#define C_ 256
#define L_ 16384
#define CL_ (C_*L_)

typedef unsigned int u32;
typedef unsigned short u16;
typedef __bf16 bf16_t;
typedef bf16_t bf16x8 __attribute__((ext_vector_type(8)));
typedef float f32x4 __attribute__((ext_vector_type(4)));

__device__ __forceinline__ float bf2f(u16 v){ return __builtin_bit_cast(float, ((u32)v)<<16); }
__device__ __forceinline__ u16 f2bf(float f){
  u32 u = __builtin_bit_cast(u32, f);
  u32 r = u + 0x7FFFu + ((u>>16)&1u);
  return (u16)(r>>16);
}
__device__ __forceinline__ u32 pack2(float a, float b){ return (u32)f2bf(a) | ((u32)f2bf(b)<<16); }

__device__ __forceinline__ void async_load16(const void* g, void* s){
  __builtin_amdgcn_global_load_lds((const __attribute__((address_space(1))) void*)g,
                                   (__attribute__((address_space(3))) void*)s, 16, 0, 0);
}

// ---------------- weight transpose+downcast kernel ----------------
// fp32 W(R x Cc) row-major -> bf16 W^T(Cc x R)
__global__ void wtrans_kernel(const float* __restrict__ qkvw, const float* __restrict__ projw,
                              const float* __restrict__ f1w, const float* __restrict__ f2w,
                              u16* __restrict__ qkvT, u16* __restrict__ projT,
                              u16* __restrict__ f1T, u16* __restrict__ f2T)
{
  __shared__ u16 tile[32][33];
  int id = blockIdx.x;
  const float* src; u16* dst; int R, Cc;
  if (id < 192){ src = qkvw; dst = qkvT; R = 256; Cc = 768; }
  else if (id < 192+64){ id -= 192; src = projw; dst = projT; R = 256; Cc = 256; }
  else if (id < 192+64+256){ id -= 192+64; src = f1w; dst = f1T; R = 256; Cc = 1024; }
  else { id -= 192+64+256; src = f2w; dst = f2T; R = 1024; Cc = 256; }
  int ctiles = Cc >> 5;
  int r0 = (id / ctiles) << 5, c0 = (id % ctiles) << 5;
  int tx = threadIdx.x & 31, ty = threadIdx.x >> 5;
  #pragma unroll
  for (int i = 0; i < 4; ++i){
    int r = ty + 8*i;
    tile[r][tx] = f2bf(src[(size_t)(r0 + r)*Cc + c0 + tx]);
  }
  __syncthreads();
  #pragma unroll
  for (int i = 0; i < 4; ++i){
    int c = ty + 8*i;
    dst[(size_t)(c0 + c)*R + r0 + tx] = tile[tx][c];
  }
}

// ---------------- GEMM helpers (K-step 32) ----------------
// Wl layout: chunk ntile (0..15, 1KB each); slot s (0..63)*16B holds
// WT[ntile*16 + (s&15)][koff + (s>>4)*8 .. +8)   -- matches B-frag lane read
__device__ __forceinline__ void stageW32(const u16* __restrict__ base, int stride, int koff,
                                         u16* Wl, int w, int l)
{
  #pragma unroll
  for (int ii = 0; ii < 2; ++ii){
    int chunk = 2*w + ii;
    int row = chunk*16 + (l & 15);
    const u16* src = base + (size_t)row*stride + koff + ((l>>4)<<3);
    async_load16(src, (char*)Wl + chunk*1024 + l*16);
  }
}

// A tile layout: byte = t*512 + ((2k) ^ ((t&7)<<4)), t in [0,64), k in [0,256)
__device__ __forceinline__ void mfma_block32(const u16* Abase, const u16* Wl, int k0, int ntb,
                                             int l, f32x4 acc[4][2])
{
  bf16x8 a[4];
  #pragma unroll
  for (int m = 0; m < 4; ++m){
    int t = m*16 + (l & 15);
    int off = t*512 + ((2*(k0 + ((l>>4)<<3))) ^ ((t&7)<<4));
    a[m] = *(const bf16x8*)((const char*)Abase + off);
  }
  #pragma unroll
  for (int n2 = 0; n2 < 2; ++n2){
    bf16x8 bb = *(const bf16x8*)((const char*)Wl + ((ntb + n2)*64 + l)*16);
    #pragma unroll
    for (int m = 0; m < 4; ++m)
      acc[m][n2] = __builtin_amdgcn_mfma_f32_16x16x32_bf16(a[m], bb, acc[m][n2], 0, 0, 0);
  }
}

__device__ __forceinline__ void gemm32(const u16* Abase, const u16* __restrict__ Wsrc,
                                       int wstride, int kbase, u16* Wl,
                                       int w, int l, int ntb, f32x4 acc[4][2])
{
  #pragma unroll 1
  for (int k0 = 0; k0 < 256; k0 += 32){
    __syncthreads();                     // Wl free / prev phase done
    stageW32(Wsrc, wstride, kbase + k0, Wl, w, l);
    __syncthreads();                     // drains vmcnt -> Wl ready
    mfma_block32(Abase, Wl, k0, ntb, l, acc);
  }
}

// ---------------- fully fused block kernel ----------------
// block = 64 tokens (original positions (blk*64+4+t) mod L), 512 threads, 80 KiB LDS
__launch_bounds__(512, 4)
__global__ void swin_fused_kernel(const float* __restrict__ x,
                                  const float* __restrict__ n1w, const float* __restrict__ n1b,
                                  const float* __restrict__ n2w, const float* __restrict__ n2b,
                                  const u16* __restrict__ qkvT, const u16* __restrict__ projT,
                                  const float* __restrict__ projb,
                                  const u16* __restrict__ f1T, const float* __restrict__ f1b,
                                  const u16* __restrict__ f2T, const float* __restrict__ f2b,
                                  float* __restrict__ out)
{
  __shared__ u16 smem[40960];            // 80 KiB exactly -> 2 blocks/CU
  u16* Buf1 = smem;                      // 0..32K  : A-ln1 -> raw dump -> A-ln2
  u16* Buf2 = smem + 16384;              // 32..64K : Q -> K -> V -> O -> xt1 -> H
  u16* Wl   = smem + 32768;              // 64..80K : weight stage / LN1 scratch

  const int tid = threadIdx.x;
  const int w = tid >> 6;
  const int l = tid & 63;
  const int bb = blockIdx.x >> 8;
  const int blkl = blockIdx.x & 255;
  const int l0 = blkl*64 + 4;
  const float* xb = x + (size_t)bb*CL_;
  const int ntb = w*2;

  // ---- phase 1: load x (8 consecutive channels x 4 tokens per thread), LN1 ----
  const int q4 = tid & 15, cg = tid >> 4;        // token-quad, channel-group(8)
  int lq = l0 + 4*q4; if (lq >= L_) lq -= L_;
  float4 xr[8];
  float s1[4] = {0.f,0.f,0.f,0.f};
  float s2[4] = {0.f,0.f,0.f,0.f};
  #pragma unroll
  for (int ci = 0; ci < 8; ++ci){
    int c = cg*8 + ci;
    float4 d = *(const float4*)(xb + (size_t)c*L_ + lq);
    xr[ci] = d;
    s1[0]+=d.x; s2[0]+=d.x*d.x;  s1[1]+=d.y; s2[1]+=d.y*d.y;
    s1[2]+=d.z; s2[2]+=d.z*d.z;  s1[3]+=d.w; s2[3]+=d.w*d.w;
  }
  #pragma unroll
  for (int off = 16; off < 64; off <<= 1){
    #pragma unroll
    for (int jj = 0; jj < 4; ++jj){
      s1[jj] += __shfl_xor(s1[jj], off);
      s2[jj] += __shfl_xor(s2[jj], off);
    }
  }
  float* red = (float*)Wl;          // [2][8][64] partials
  float* stats = red + 1024;        // [64][2]
  if (l < 16){
    #pragma unroll
    for (int jj = 0; jj < 4; ++jj){
      red[w*64 + 4*l + jj] = s1[jj];
      red[512 + w*64 + 4*l + jj] = s2[jj];
    }
  }
  __syncthreads();
  if (tid < 64){
    float a = 0.f, b2 = 0.f;
    #pragma unroll
    for (int ww = 0; ww < 8; ++ww){ a += red[ww*64 + tid]; b2 += red[512 + ww*64 + tid]; }
    float mu = a * (1.f/256.f);
    float var = fmaxf(b2 * (1.f/256.f) - mu*mu, 0.f);
    stats[2*tid] = mu;
    stats[2*tid+1] = rsqrtf(var + 1e-5f);
  }
  __syncthreads();

  u32 praw[4][4];                    // raw x, bf16-packed: [jj][c-pair]
  #pragma unroll
  for (int jj = 0; jj < 4; ++jj){
    int t = 4*q4 + jj;
    float mu = stats[2*t], rs = stats[2*t+1];
    u32 aw[4];
    #pragma unroll
    for (int cp = 0; cp < 4; ++cp){
      int c0c = cg*8 + 2*cp;
      float v0 = ((const float*)&xr[2*cp])[jj];
      float v1 = ((const float*)&xr[2*cp+1])[jj];
      aw[cp] = pack2((v0-mu)*rs*n1w[c0c] + n1b[c0c], (v1-mu)*rs*n1w[c0c+1] + n1b[c0c+1]);
      praw[jj][cp] = pack2(v0, v1);
    }
    *(uint4*)((char*)Buf1 + t*512 + ((cg*16) ^ ((t&7)<<4))) = make_uint4(aw[0],aw[1],aw[2],aw[3]);
  }

  // ---- Q GEMM -> Buf2 ----
  {
    f32x4 acc[4][2];
    #pragma unroll
    for (int m = 0; m < 4; ++m){ acc[m][0] = (f32x4){0,0,0,0}; acc[m][1] = (f32x4){0,0,0,0}; }
    gemm32(Buf1, qkvT, 256, 0, Wl, w, l, ntb, acc);
    __syncthreads();   // last mfma (Wl reads) done; Buf2 writes are fresh region
    #pragma unroll
    for (int m = 0; m < 4; ++m)
      #pragma unroll
      for (int n2 = 0; n2 < 2; ++n2)
        #pragma unroll
        for (int jj = 0; jj < 4; ++jj){
          int t = m*16 + ((l>>4)<<2) + jj;
          int c = (w<<5) + (n2<<4) + (l&15);
          *(u16*)((char*)Buf2 + t*512 + ((2*c) ^ ((t&7)<<4))) = f2bf(acc[m][n2][jj]);
        }
  }
  __syncthreads();

  // ---- read Q into regs (thread = (w=window, h, r)) ----
  const int hh = (tid >> 3) & 7, rr = tid & 7;
  const int tq = w*8 + rr;
  float qf[32];
  {
    #pragma unroll
    for (int g = 0; g < 4; ++g){
      uint4 dq = *(const uint4*)((char*)Buf2 + tq*512 + ((hh*64 + 16*g) ^ ((tq&7)<<4)));
      qf[g*8+0] = bf2f((u16)dq.x); qf[g*8+1] = bf2f((u16)(dq.x>>16));
      qf[g*8+2] = bf2f((u16)dq.y); qf[g*8+3] = bf2f((u16)(dq.y>>16));
      qf[g*8+4] = bf2f((u16)dq.z); qf[g*8+5] = bf2f((u16)(dq.z>>16));
      qf[g*8+6] = bf2f((u16)dq.w); qf[g*8+7] = bf2f((u16)(dq.w>>16));
    }
  }

  // ---- K GEMM -> Buf2 (qf reads complete before first internal barrier) ----
  {
    f32x4 acc[4][2];
    #pragma unroll
    for (int m = 0; m < 4; ++m){ acc[m][0] = (f32x4){0,0,0,0}; acc[m][1] = (f32x4){0,0,0,0}; }
    gemm32(Buf1, qkvT + 65536, 256, 0, Wl, w, l, ntb, acc);
    __syncthreads();
    #pragma unroll
    for (int m = 0; m < 4; ++m)
      #pragma unroll
      for (int n2 = 0; n2 < 2; ++n2)
        #pragma unroll
        for (int jj = 0; jj < 4; ++jj){
          int t = m*16 + ((l>>4)<<2) + jj;
          int c = (w<<5) + (n2<<4) + (l&15);
          *(u16*)((char*)Buf2 + t*512 + ((2*c) ^ ((t&7)<<4))) = f2bf(acc[m][n2][jj]);
        }
  }
  __syncthreads();

  // ---- scores + softmax (pr kept in regs) ----
  float pr[8];
  {
    u32 kr[16];
    #pragma unroll
    for (int g = 0; g < 4; ++g){
      uint4 dk = *(const uint4*)((char*)Buf2 + tq*512 + ((hh*64 + 16*g) ^ ((tq&7)<<4)));
      kr[g*4+0] = dk.x; kr[g*4+1] = dk.y; kr[g*4+2] = dk.z; kr[g*4+3] = dk.w;
    }
    float s[8];
    #pragma unroll
    for (int j = 0; j < 8; ++j){
      float dot = 0.f;
      #pragma unroll
      for (int reg = 0; reg < 16; ++reg){
        u32 kj = (u32)__shfl((int)kr[reg], j, 8);
        dot += qf[2*reg]   * bf2f((u16)kj);
        dot += qf[2*reg+1] * bf2f((u16)(kj>>16));
      }
      s[j] = dot * 0.17677669529663687f;
    }
    float mx = s[0];
    #pragma unroll
    for (int j = 1; j < 8; ++j) mx = fmaxf(mx, s[j]);
    float sum = 0.f;
    #pragma unroll
    for (int j = 0; j < 8; ++j){ pr[j] = __expf(s[j]-mx); sum += pr[j]; }
    float inv = 1.0f / sum;
    #pragma unroll
    for (int j = 0; j < 8; ++j) pr[j] *= inv;
  }

  // ---- V GEMM -> Buf2 (kr consumed already) ----
  {
    f32x4 acc[4][2];
    #pragma unroll
    for (int m = 0; m < 4; ++m){ acc[m][0] = (f32x4){0,0,0,0}; acc[m][1] = (f32x4){0,0,0,0}; }
    gemm32(Buf1, qkvT + 131072, 256, 0, Wl, w, l, ntb, acc);
    __syncthreads();
    #pragma unroll
    for (int m = 0; m < 4; ++m)
      #pragma unroll
      for (int n2 = 0; n2 < 2; ++n2)
        #pragma unroll
        for (int jj = 0; jj < 4; ++jj){
          int t = m*16 + ((l>>4)<<2) + jj;
          int c = (w<<5) + (n2<<4) + (l&15);
          *(u16*)((char*)Buf2 + t*512 + ((2*c) ^ ((t&7)<<4))) = f2bf(acc[m][n2][jj]);
        }
  }
  __syncthreads();

  // ---- raw x dump into Buf1 (A-ln1 fully consumed by V GEMM) ----
  #pragma unroll
  for (int jj = 0; jj < 4; ++jj){
    int t = 4*q4 + jj;
    *(uint4*)((char*)Buf1 + t*512 + ((cg*16) ^ ((t&7)<<4))) =
        make_uint4(praw[jj][0], praw[jj][1], praw[jj][2], praw[jj][3]);
  }

  // ---- PV: read V rows, write O in place (disjoint per-thread ranges) ----
  {
    u32 vr[16];
    #pragma unroll
    for (int g = 0; g < 4; ++g){
      uint4 dv = *(const uint4*)((char*)Buf2 + tq*512 + ((hh*64 + 16*g) ^ ((tq&7)<<4)));
      vr[g*4+0] = dv.x; vr[g*4+1] = dv.y; vr[g*4+2] = dv.z; vr[g*4+3] = dv.w;
    }
    float of[32];
    #pragma unroll
    for (int d = 0; d < 32; ++d) of[d] = 0.f;
    #pragma unroll
    for (int j = 0; j < 8; ++j){
      float pj = pr[j];
      #pragma unroll
      for (int reg = 0; reg < 16; ++reg){
        u32 vj = (u32)__shfl((int)vr[reg], j, 8);
        of[2*reg]   += pj*bf2f((u16)vj);
        of[2*reg+1] += pj*bf2f((u16)(vj>>16));
      }
    }
    #pragma unroll
    for (int g = 0; g < 4; ++g){
      uint4 o;
      o.x = pack2(of[g*8+0], of[g*8+1]);
      o.y = pack2(of[g*8+2], of[g*8+3]);
      o.z = pack2(of[g*8+4], of[g*8+5]);
      o.w = pack2(of[g*8+6], of[g*8+7]);
      *(uint4*)((char*)Buf2 + tq*512 + ((hh*64 + 16*g) ^ ((tq&7)<<4))) = o;
    }
  }

  // ---- proj GEMM (A=Buf2=O) ----
  u32 xt1p[4][2][2];                 // xt1 residual, bf16-packed (jj pairs)
  {
    f32x4 acc[4][2];
    #pragma unroll
    for (int m = 0; m < 4; ++m){ acc[m][0] = (f32x4){0,0,0,0}; acc[m][1] = (f32x4){0,0,0,0}; }
    gemm32(Buf2, projT, 256, 0, Wl, w, l, ntb, acc);
    __syncthreads();                 // all A-frag reads of Buf2 done before overwrite
    #pragma unroll
    for (int m = 0; m < 4; ++m)
      #pragma unroll
      for (int n2 = 0; n2 < 2; ++n2){
        float vv[4];
        #pragma unroll
        for (int jj = 0; jj < 4; ++jj){
          int t = m*16 + ((l>>4)<<2) + jj;
          int c = (w<<5) + (n2<<4) + (l&15);
          float rv = bf2f(*(const u16*)((char*)Buf1 + t*512 + ((2*c) ^ ((t&7)<<4))));
          float v = acc[m][n2][jj] + projb[c] + rv;
          vv[jj] = v;
          *(u16*)((char*)Buf2 + t*512 + 2*c) = f2bf(v);   // xt1 tile, linear
        }
        xt1p[m][n2][0] = pack2(vv[0], vv[1]);
        xt1p[m][n2][1] = pack2(vv[2], vv[3]);
      }
  }
  __syncthreads();

  // ---- LN2 (read Buf2 linear rows, write Buf1 swizzled A-tile) ----
  {
    float4 wv = *(const float4*)(n2w + 4*l);
    float4 bv = *(const float4*)(n2b + 4*l);
    #pragma unroll 1
    for (int r = 0; r < 8; ++r){
      int t = w*8 + r;
      uint2 d = *(const uint2*)((char*)Buf2 + t*512 + 8*l);
      float f0 = bf2f((u16)d.x), f1 = bf2f((u16)(d.x>>16));
      float f2 = bf2f((u16)d.y), f3 = bf2f((u16)(d.y>>16));
      float ls1 = f0+f1+f2+f3;
      float ls2 = f0*f0+f1*f1+f2*f2+f3*f3;
      #pragma unroll
      for (int off = 1; off < 64; off <<= 1){
        ls1 += __shfl_xor(ls1, off);
        ls2 += __shfl_xor(ls2, off);
      }
      float mu = ls1 * (1.f/256.f);
      float var = fmaxf(ls2 * (1.f/256.f) - mu*mu, 0.f);
      float rs = rsqrtf(var + 1e-5f);
      uint2 pp;
      pp.x = pack2((f0-mu)*rs*wv.x+bv.x, (f1-mu)*rs*wv.y+bv.y);
      pp.y = pack2((f2-mu)*rs*wv.z+bv.z, (f3-mu)*rs*wv.w+bv.w);
      *(uint2*)((char*)Buf1 + t*512 + ((8*l) ^ ((t&7)<<4))) = pp;
    }
  }

  // ---- FF: 4 hidden chunks of 256; H lives in Buf2 ----
  f32x4 acc2[4][2];
  #pragma unroll
  for (int m = 0; m < 4; ++m){ acc2[m][0] = (f32x4){0,0,0,0}; acc2[m][1] = (f32x4){0,0,0,0}; }
  #pragma unroll 1
  for (int c2 = 0; c2 < 4; ++c2){
    f32x4 acc1[4][2];
    #pragma unroll
    for (int m = 0; m < 4; ++m){ acc1[m][0] = (f32x4){0,0,0,0}; acc1[m][1] = (f32x4){0,0,0,0}; }
    gemm32(Buf1, f1T + (size_t)c2*65536, 256, 0, Wl, w, l, ntb, acc1);
    __syncthreads();                 // prior Buf2 readers (LN2 / FF2) done
    #pragma unroll
    for (int m = 0; m < 4; ++m)
      #pragma unroll
      for (int n2 = 0; n2 < 2; ++n2)
        #pragma unroll
        for (int jj = 0; jj < 4; ++jj){
          int t = m*16 + ((l>>4)<<2) + jj;
          int c = (w<<5) + (n2<<4) + (l&15);
          float xv = acc1[m][n2][jj] + f1b[c2*256 + c];
          float g = 0.5f*xv*(1.f + erff(xv*0.70710678118654752f));
          *(u16*)((char*)Buf2 + t*512 + ((2*c) ^ ((t&7)<<4))) = f2bf(g);
        }
    gemm32(Buf2, f2T, 1024, c2*256, Wl, w, l, ntb, acc2);
  }
  __syncthreads();

  // ---- final epilogue: +f2b +xt1(regs) -> fp32 stage across Buf1+Buf2 (64KB) ----
  float* OutF = (float*)smem;        // [c 0..255][t 0..63] fp32, 16B-XOR swizzled
  #pragma unroll
  for (int m = 0; m < 4; ++m)
    #pragma unroll
    for (int n2 = 0; n2 < 2; ++n2)
      #pragma unroll
      for (int jj = 0; jj < 4; ++jj){
        int t = m*16 + ((l>>4)<<2) + jj;
        int c = (w<<5) + (n2<<4) + (l&15);
        u32 p = xt1p[m][n2][jj>>1];
        float rv = bf2f((u16)((jj&1) ? (p>>16) : (p&0xFFFF)));
        float v = acc2[m][n2][jj] + f2b[c] + rv;
        *(float*)((char*)OutF + c*256 + ((4*t) ^ ((c&15)<<4))) = v;
      }
  __syncthreads();

  // ---- transposed global write out[b][c][(l0+4qd..) mod L] ----
  float* ob = out + (size_t)bb*CL_;
  #pragma unroll
  for (int ii = 0; ii < 8; ++ii){
    int id = tid + ii*512;
    int c = id >> 4, qd = id & 15;
    int lw = l0 + 4*qd; if (lw >= L_) lw -= L_;
    float4 vv = *(const float4*)((char*)OutF + c*256 + ((16*qd) ^ ((c&15)<<4)));
    *(float4*)(ob + (size_t)c*L_ + lw) = vv;
  }
}

// ---------------- launch ----------------
extern "C" void kernel_launch(void* const* d_in, const int* in_sizes, int n_in,
                              void* d_out, int out_size, void* d_ws, size_t ws_size,
                              hipStream_t stream)
{
  const float* x     = (const float*)d_in[0];
  const float* n1w   = (const float*)d_in[1];
  const float* n1b   = (const float*)d_in[2];
  const float* n2w   = (const float*)d_in[3];
  const float* n2b   = (const float*)d_in[4];
  const float* qkvw  = (const float*)d_in[5];
  const float* projw = (const float*)d_in[6];
  const float* projb = (const float*)d_in[7];
  const float* f1w   = (const float*)d_in[8];
  const float* f1b   = (const float*)d_in[9];
  const float* f2w   = (const float*)d_in[10];
  const float* f2b   = (const float*)d_in[11];
  float* out = (float*)d_out;

  u16* ws    = (u16*)d_ws;
  u16* qkvT  = ws;                      // 768*256
  u16* projT = qkvT + 196608;           // 256*256
  u16* f1T   = projT + 65536;           // 1024*256
  u16* f2T   = f1T + 262144;            // 256*1024  (total 1.57 MB bf16)

  hipLaunchKernelGGL(wtrans_kernel, dim3(768), dim3(256), 0, stream,
                     qkvw, projw, f1w, f2w, qkvT, projT, f1T, f2T);
  hipLaunchKernelGGL(swin_fused_kernel, dim3(2048), dim3(512), 0, stream,
                     x, n1w, n1b, n2w, n2b, qkvT, projT, projb, f1T, f1b, f2T, f2b, out);
}

// Round 5
// 945.751 us; speedup vs baseline: 1.1754x; 1.1129x over previous
//
#include <hip/hip_runtime.h>
#include <hip/hip_bf16.h>

#define C_ 256
#define L_ 16384
#define CL_ (C_*L_)

typedef unsigned int u32;
typedef unsigned short u16;
typedef __bf16 bf16_t;
typedef bf16_t bf16x8 __attribute__((ext_vector_type(8)));
typedef float f32x4 __attribute__((ext_vector_type(4)));

__device__ __forceinline__ float bf2f(u16 v){ return __builtin_bit_cast(float, ((u32)v)<<16); }
__device__ __forceinline__ u16 f2bf(float f){
  u32 u = __builtin_bit_cast(u32, f);
  u32 r = u + 0x7FFFu + ((u>>16)&1u);
  return (u16)(r>>16);
}
__device__ __forceinline__ u32 pack2(float a, float b){ return (u32)f2bf(a) | ((u32)f2bf(b)<<16); }

// ---------------- weight PACK kernel ----------------
// Packs fp32 W[k][n] into per-lane MFMA B-fragment order, bf16:
// frag(kstep,nt,lane) 16B = W^T[nt*16+(l&15)][kstep*32 + (l>>4)*8 .. +8)
// layout: pk[((kstep*16+nt)*64 + l)*8 u16]. One 256-col slice = 65536 u16 (128KB).
__global__ void wpack_kernel(const float* __restrict__ qkvw, const float* __restrict__ projw,
                             const float* __restrict__ f1w, const float* __restrict__ f2w,
                             u16* __restrict__ pq, u16* __restrict__ pp,
                             u16* __restrict__ p1, u16* __restrict__ p2)
{
  int bid = blockIdx.x, tid = threadIdx.x;
  const float* src; u16* dst; int stride, n, k;
  if (bid < 96){                       // qkv: 3 slices x 8 ksteps x 16 nt x 64 l
    int f = bid*256 + tid;
    int l = f & 63, nt = (f>>6) & 15, kk = f>>10;
    int s = kk>>3, ks = kk&7;
    stride = 768; src = qkvw;
    n = s*256 + nt*16 + (l&15);
    k = ks*32 + ((l>>4)<<3);
    dst = pq + (size_t)s*65536 + ((size_t)(ks*16 + nt)*64 + l)*8;
  } else if (bid < 128){               // proj: 8 ksteps
    int f = (bid-96)*256 + tid;
    int l = f & 63, nt = (f>>6) & 15, ks = f>>10;
    stride = 256; src = projw;
    n = nt*16 + (l&15);
    k = ks*32 + ((l>>4)<<3);
    dst = pp + ((size_t)(ks*16 + nt)*64 + l)*8;
  } else if (bid < 256){               // ff1: 4 slices x 8 ksteps
    int f = (bid-128)*256 + tid;
    int l = f & 63, nt = (f>>6) & 15, kk = f>>10;
    int c2 = kk>>3, ks = kk&7;
    stride = 1024; src = f1w;
    n = c2*256 + nt*16 + (l&15);
    k = ks*32 + ((l>>4)<<3);
    dst = p1 + (size_t)c2*65536 + ((size_t)(ks*16 + nt)*64 + l)*8;
  } else {                             // ff2: K=1024 -> 32 global ksteps
    int f = (bid-256)*256 + tid;
    int l = f & 63, nt = (f>>6) & 15, ks = f>>10;     // ks 0..31
    stride = 256; src = f2w;
    n = nt*16 + (l&15);
    k = ks*32 + ((l>>4)<<3);
    dst = p2 + ((size_t)(ks*16 + nt)*64 + l)*8;
  }
  u16 v[8];
  #pragma unroll
  for (int j = 0; j < 8; ++j) v[j] = f2bf(src[(size_t)(k+j)*stride + n]);
  uint4 o;
  o.x = (u32)v[0] | ((u32)v[1]<<16);
  o.y = (u32)v[2] | ((u32)v[3]<<16);
  o.z = (u32)v[4] | ((u32)v[5]<<16);
  o.w = (u32)v[6] | ((u32)v[7]<<16);
  *(uint4*)dst = o;
}

// ---------------- barrier-free GEMM: A from LDS, B direct global (packed) ----------------
// A tile layout: byte = t*512 + ((2k) ^ ((t&7)<<4)), t in [0,64), k in [0,256)
__device__ __forceinline__ void gemmP(const u16* Abase, const u16* __restrict__ pk,
                                      int l, int ntb, f32x4 acc[4][2])
{
  #pragma unroll
  for (int ks = 0; ks < 8; ++ks){
    bf16x8 b0 = *(const bf16x8*)(pk + ((size_t)(ks*16 + ntb    )*64 + l)*8);
    bf16x8 b1 = *(const bf16x8*)(pk + ((size_t)(ks*16 + ntb + 1)*64 + l)*8);
    int k0 = ks*32;
    bf16x8 a[4];
    #pragma unroll
    for (int m = 0; m < 4; ++m){
      int t = m*16 + (l & 15);
      int off = t*512 + ((2*(k0 + ((l>>4)<<3))) ^ ((t&7)<<4));
      a[m] = *(const bf16x8*)((const char*)Abase + off);
    }
    #pragma unroll
    for (int m = 0; m < 4; ++m){
      acc[m][0] = __builtin_amdgcn_mfma_f32_16x16x32_bf16(a[m], b0, acc[m][0], 0, 0, 0);
      acc[m][1] = __builtin_amdgcn_mfma_f32_16x16x32_bf16(a[m], b1, acc[m][1], 0, 0, 0);
    }
  }
}

#define ZERO_ACC(A) { _Pragma("unroll") for (int m_ = 0; m_ < 4; ++m_){ A[m_][0] = (f32x4){0,0,0,0}; A[m_][1] = (f32x4){0,0,0,0}; } }

// ---------------- fully fused block kernel ----------------
// block = 64 tokens (original positions (blk*64+4+t) mod L), 512 threads, ~68.5 KiB LDS
__launch_bounds__(512, 4)
__global__ void swin_fused_kernel(const float* __restrict__ x,
                                  const float* __restrict__ n1w, const float* __restrict__ n1b,
                                  const float* __restrict__ n2w, const float* __restrict__ n2b,
                                  const u16* __restrict__ pkq, const u16* __restrict__ pkp,
                                  const float* __restrict__ projb,
                                  const u16* __restrict__ pk1, const float* __restrict__ f1b,
                                  const u16* __restrict__ pk2, const float* __restrict__ f2b,
                                  float* __restrict__ out)
{
  __shared__ u16 smem[35072];            // 68.5 KiB -> 2 blocks/CU
  u16* Buf1 = smem;                      // 32K: A-ln1 -> raw dump -> A-ln2
  u16* Buf2 = smem + 16384;              // 32K: Q -> K -> V -> O -> xt1 -> H
  float* redF   = (float*)(smem + 32768);  // [2][8][64]
  float* statsF = redF + 1024;             // [64][2]

  const int tid = threadIdx.x;
  const int w = tid >> 6;
  const int l = tid & 63;
  const int bb = blockIdx.x >> 8;
  const int blkl = blockIdx.x & 255;
  const int l0 = blkl*64 + 4;
  const float* xb = x + (size_t)bb*CL_;
  const int ntb = w*2;

  // ---- phase 1: load x (8 consecutive channels x 4 tokens per thread), LN1 ----
  const int q4 = tid & 15, cg = tid >> 4;
  int lq = l0 + 4*q4; if (lq >= L_) lq -= L_;
  float4 xr[8];
  float s1[4] = {0.f,0.f,0.f,0.f};
  float s2[4] = {0.f,0.f,0.f,0.f};
  #pragma unroll
  for (int ci = 0; ci < 8; ++ci){
    int c = cg*8 + ci;
    float4 d = *(const float4*)(xb + (size_t)c*L_ + lq);
    xr[ci] = d;
    s1[0]+=d.x; s2[0]+=d.x*d.x;  s1[1]+=d.y; s2[1]+=d.y*d.y;
    s1[2]+=d.z; s2[2]+=d.z*d.z;  s1[3]+=d.w; s2[3]+=d.w*d.w;
  }
  #pragma unroll
  for (int off = 16; off < 64; off <<= 1){
    #pragma unroll
    for (int jj = 0; jj < 4; ++jj){
      s1[jj] += __shfl_xor(s1[jj], off);
      s2[jj] += __shfl_xor(s2[jj], off);
    }
  }
  if (l < 16){
    #pragma unroll
    for (int jj = 0; jj < 4; ++jj){
      redF[w*64 + 4*l + jj] = s1[jj];
      redF[512 + w*64 + 4*l + jj] = s2[jj];
    }
  }
  __syncthreads();
  if (tid < 64){
    float a = 0.f, b2 = 0.f;
    #pragma unroll
    for (int ww = 0; ww < 8; ++ww){ a += redF[ww*64 + tid]; b2 += redF[512 + ww*64 + tid]; }
    float mu = a * (1.f/256.f);
    float var = fmaxf(b2 * (1.f/256.f) - mu*mu, 0.f);
    statsF[2*tid] = mu;
    statsF[2*tid+1] = rsqrtf(var + 1e-5f);
  }
  __syncthreads();

  u32 praw[4][4];
  #pragma unroll
  for (int jj = 0; jj < 4; ++jj){
    int t = 4*q4 + jj;
    float mu = statsF[2*t], rs = statsF[2*t+1];
    u32 aw[4];
    #pragma unroll
    for (int cp = 0; cp < 4; ++cp){
      int c0c = cg*8 + 2*cp;
      float v0 = ((const float*)&xr[2*cp])[jj];
      float v1 = ((const float*)&xr[2*cp+1])[jj];
      aw[cp] = pack2((v0-mu)*rs*n1w[c0c] + n1b[c0c], (v1-mu)*rs*n1w[c0c+1] + n1b[c0c+1]);
      praw[jj][cp] = pack2(v0, v1);
    }
    *(uint4*)((char*)Buf1 + t*512 + ((cg*16) ^ ((t&7)<<4))) = make_uint4(aw[0],aw[1],aw[2],aw[3]);
  }
  __syncthreads();                       // A-ln1 ready

  // ---- Q GEMM -> Buf2 ----
  {
    f32x4 acc[4][2]; ZERO_ACC(acc);
    gemmP(Buf1, pkq, l, ntb, acc);
    #pragma unroll
    for (int m = 0; m < 4; ++m)
      #pragma unroll
      for (int n2 = 0; n2 < 2; ++n2)
        #pragma unroll
        for (int jj = 0; jj < 4; ++jj){
          int t = m*16 + ((l>>4)<<2) + jj;
          int c = (w<<5) + (n2<<4) + (l&15);
          *(u16*)((char*)Buf2 + t*512 + ((2*c) ^ ((t&7)<<4))) = f2bf(acc[m][n2][jj]);
        }
  }
  __syncthreads();

  // ---- read Q into regs ----
  const int hh = (tid >> 3) & 7, rr = tid & 7;
  const int tq = w*8 + rr;
  float qf[32];
  #pragma unroll
  for (int g = 0; g < 4; ++g){
    uint4 dq = *(const uint4*)((char*)Buf2 + tq*512 + ((hh*64 + 16*g) ^ ((tq&7)<<4)));
    qf[g*8+0] = bf2f((u16)dq.x); qf[g*8+1] = bf2f((u16)(dq.x>>16));
    qf[g*8+2] = bf2f((u16)dq.y); qf[g*8+3] = bf2f((u16)(dq.y>>16));
    qf[g*8+4] = bf2f((u16)dq.z); qf[g*8+5] = bf2f((u16)(dq.z>>16));
    qf[g*8+6] = bf2f((u16)dq.w); qf[g*8+7] = bf2f((u16)(dq.w>>16));
  }
  __syncthreads();                       // Q reads done before K-epi overwrite

  // ---- K GEMM -> Buf2 ----
  {
    f32x4 acc[4][2]; ZERO_ACC(acc);
    gemmP(Buf1, pkq + 65536, l, ntb, acc);
    #pragma unroll
    for (int m = 0; m < 4; ++m)
      #pragma unroll
      for (int n2 = 0; n2 < 2; ++n2)
        #pragma unroll
        for (int jj = 0; jj < 4; ++jj){
          int t = m*16 + ((l>>4)<<2) + jj;
          int c = (w<<5) + (n2<<4) + (l&15);
          *(u16*)((char*)Buf2 + t*512 + ((2*c) ^ ((t&7)<<4))) = f2bf(acc[m][n2][jj]);
        }
  }
  __syncthreads();

  // ---- scores + softmax ----
  float pr[8];
  {
    u32 kr[16];
    #pragma unroll
    for (int g = 0; g < 4; ++g){
      uint4 dk = *(const uint4*)((char*)Buf2 + tq*512 + ((hh*64 + 16*g) ^ ((tq&7)<<4)));
      kr[g*4+0] = dk.x; kr[g*4+1] = dk.y; kr[g*4+2] = dk.z; kr[g*4+3] = dk.w;
    }
    float s[8];
    #pragma unroll
    for (int j = 0; j < 8; ++j){
      float dot = 0.f;
      #pragma unroll
      for (int reg = 0; reg < 16; ++reg){
        u32 kj = (u32)__shfl((int)kr[reg], j, 8);
        dot += qf[2*reg]   * bf2f((u16)kj);
        dot += qf[2*reg+1] * bf2f((u16)(kj>>16));
      }
      s[j] = dot * 0.17677669529663687f;
    }
    float mx = s[0];
    #pragma unroll
    for (int j = 1; j < 8; ++j) mx = fmaxf(mx, s[j]);
    float sum = 0.f;
    #pragma unroll
    for (int j = 0; j < 8; ++j){ pr[j] = __expf(s[j]-mx); sum += pr[j]; }
    float inv = 1.0f / sum;
    #pragma unroll
    for (int j = 0; j < 8; ++j) pr[j] *= inv;
  }
  __syncthreads();                       // K reads done before V-epi overwrite

  // ---- V GEMM -> Buf2; then raw dump -> Buf1 ----
  {
    f32x4 acc[4][2]; ZERO_ACC(acc);
    gemmP(Buf1, pkq + 131072, l, ntb, acc);
    __syncthreads();                     // all Buf1 A-frag reads done
    #pragma unroll
    for (int m = 0; m < 4; ++m)
      #pragma unroll
      for (int n2 = 0; n2 < 2; ++n2)
        #pragma unroll
        for (int jj = 0; jj < 4; ++jj){
          int t = m*16 + ((l>>4)<<2) + jj;
          int c = (w<<5) + (n2<<4) + (l&15);
          *(u16*)((char*)Buf2 + t*512 + ((2*c) ^ ((t&7)<<4))) = f2bf(acc[m][n2][jj]);
        }
    #pragma unroll
    for (int jj = 0; jj < 4; ++jj){
      int t = 4*q4 + jj;
      *(uint4*)((char*)Buf1 + t*512 + ((cg*16) ^ ((t&7)<<4))) =
          make_uint4(praw[jj][0], praw[jj][1], praw[jj][2], praw[jj][3]);
    }
  }
  __syncthreads();

  // ---- PV: read V rows, write O in place (per-thread disjoint) ----
  {
    u32 vr[16];
    #pragma unroll
    for (int g = 0; g < 4; ++g){
      uint4 dv = *(const uint4*)((char*)Buf2 + tq*512 + ((hh*64 + 16*g) ^ ((tq&7)<<4)));
      vr[g*4+0] = dv.x; vr[g*4+1] = dv.y; vr[g*4+2] = dv.z; vr[g*4+3] = dv.w;
    }
    float of[32];
    #pragma unroll
    for (int d = 0; d < 32; ++d) of[d] = 0.f;
    #pragma unroll
    for (int j = 0; j < 8; ++j){
      float pj = pr[j];
      #pragma unroll
      for (int reg = 0; reg < 16; ++reg){
        u32 vj = (u32)__shfl((int)vr[reg], j, 8);
        of[2*reg]   += pj*bf2f((u16)vj);
        of[2*reg+1] += pj*bf2f((u16)(vj>>16));
      }
    }
    #pragma unroll
    for (int g = 0; g < 4; ++g){
      uint4 o;
      o.x = pack2(of[g*8+0], of[g*8+1]);
      o.y = pack2(of[g*8+2], of[g*8+3]);
      o.z = pack2(of[g*8+4], of[g*8+5]);
      o.w = pack2(of[g*8+6], of[g*8+7]);
      *(uint4*)((char*)Buf2 + tq*512 + ((hh*64 + 16*g) ^ ((tq&7)<<4))) = o;
    }
  }
  __syncthreads();

  // ---- proj GEMM (A=Buf2=O) ----
  u32 xt1p[4][2][2];
  {
    f32x4 acc[4][2]; ZERO_ACC(acc);
    gemmP(Buf2, pkp, l, ntb, acc);
    __syncthreads();                     // all Buf2 O-reads done
    #pragma unroll
    for (int m = 0; m < 4; ++m)
      #pragma unroll
      for (int n2 = 0; n2 < 2; ++n2){
        float vv[4];
        #pragma unroll
        for (int jj = 0; jj < 4; ++jj){
          int t = m*16 + ((l>>4)<<2) + jj;
          int c = (w<<5) + (n2<<4) + (l&15);
          float rv = bf2f(*(const u16*)((char*)Buf1 + t*512 + ((2*c) ^ ((t&7)<<4))));
          float v = acc[m][n2][jj] + projb[c] + rv;
          vv[jj] = v;
          *(u16*)((char*)Buf2 + t*512 + 2*c) = f2bf(v);   // xt1 tile, linear
        }
        xt1p[m][n2][0] = pack2(vv[0], vv[1]);
        xt1p[m][n2][1] = pack2(vv[2], vv[3]);
      }
  }
  __syncthreads();

  // ---- LN2 (read Buf2 linear, write Buf1 swizzled) ----
  {
    float4 wv = *(const float4*)(n2w + 4*l);
    float4 bv = *(const float4*)(n2b + 4*l);
    #pragma unroll 1
    for (int r = 0; r < 8; ++r){
      int t = w*8 + r;
      uint2 d = *(const uint2*)((char*)Buf2 + t*512 + 8*l);
      float f0 = bf2f((u16)d.x), f1 = bf2f((u16)(d.x>>16));
      float f2 = bf2f((u16)d.y), f3 = bf2f((u16)(d.y>>16));
      float ls1 = f0+f1+f2+f3;
      float ls2 = f0*f0+f1*f1+f2*f2+f3*f3;
      #pragma unroll
      for (int off = 1; off < 64; off <<= 1){
        ls1 += __shfl_xor(ls1, off);
        ls2 += __shfl_xor(ls2, off);
      }
      float mu = ls1 * (1.f/256.f);
      float var = fmaxf(ls2 * (1.f/256.f) - mu*mu, 0.f);
      float rs = rsqrtf(var + 1e-5f);
      uint2 pp;
      pp.x = pack2((f0-mu)*rs*wv.x+bv.x, (f1-mu)*rs*wv.y+bv.y);
      pp.y = pack2((f2-mu)*rs*wv.z+bv.z, (f3-mu)*rs*wv.w+bv.w);
      *(uint2*)((char*)Buf1 + t*512 + ((8*l) ^ ((t&7)<<4))) = pp;
    }
  }
  __syncthreads();                       // A-ln2 ready

  // ---- FF: 4 hidden chunks of 256; H in Buf2 ----
  f32x4 acc2[4][2]; ZERO_ACC(acc2);
  #pragma unroll 1
  for (int c2 = 0; c2 < 4; ++c2){
    f32x4 acc1[4][2]; ZERO_ACC(acc1);
    gemmP(Buf1, pk1 + (size_t)c2*65536, l, ntb, acc1);
    __syncthreads();                     // prior Buf2 readers done
    #pragma unroll
    for (int m = 0; m < 4; ++m)
      #pragma unroll
      for (int n2 = 0; n2 < 2; ++n2)
        #pragma unroll
        for (int jj = 0; jj < 4; ++jj){
          int t = m*16 + ((l>>4)<<2) + jj;
          int c = (w<<5) + (n2<<4) + (l&15);
          float xv = acc1[m][n2][jj] + f1b[c2*256 + c];
          float g = 0.5f*xv*(1.f + erff(xv*0.70710678118654752f));
          *(u16*)((char*)Buf2 + t*512 + ((2*c) ^ ((t&7)<<4))) = f2bf(g);
        }
    __syncthreads();                     // H ready
    gemmP(Buf2, pk2 + (size_t)c2*65536, l, ntb, acc2);
    __syncthreads();                     // H reads done (guards next gelu-epi / OutF)
  }

  // ---- final epilogue: +f2b +xt1(regs) -> fp32 stage across Buf1+Buf2 ----
  float* OutF = (float*)smem;            // [c 0..255][t 0..63] fp32, 16B-XOR swizzled
  #pragma unroll
  for (int m = 0; m < 4; ++m)
    #pragma unroll
    for (int n2 = 0; n2 < 2; ++n2)
      #pragma unroll
      for (int jj = 0; jj < 4; ++jj){
        int t = m*16 + ((l>>4)<<2) + jj;
        int c = (w<<5) + (n2<<4) + (l&15);
        u32 p = xt1p[m][n2][jj>>1];
        float rv = bf2f((u16)((jj&1) ? (p>>16) : (p&0xFFFF)));
        float v = acc2[m][n2][jj] + f2b[c] + rv;
        *(float*)((char*)OutF + c*256 + ((4*t) ^ ((c&15)<<4))) = v;
      }
  __syncthreads();

  // ---- transposed global write out[b][c][(l0+4qd..) mod L] ----
  float* ob = out + (size_t)bb*CL_;
  #pragma unroll
  for (int ii = 0; ii < 8; ++ii){
    int id = tid + ii*512;
    int c = id >> 4, qd = id & 15;
    int lw = l0 + 4*qd; if (lw >= L_) lw -= L_;
    float4 vv = *(const float4*)((char*)OutF + c*256 + ((16*qd) ^ ((c&15)<<4)));
    *(float4*)(ob + (size_t)c*L_ + lw) = vv;
  }
}

// ---------------- launch ----------------
extern "C" void kernel_launch(void* const* d_in, const int* in_sizes, int n_in,
                              void* d_out, int out_size, void* d_ws, size_t ws_size,
                              hipStream_t stream)
{
  const float* x     = (const float*)d_in[0];
  const float* n1w   = (const float*)d_in[1];
  const float* n1b   = (const float*)d_in[2];
  const float* n2w   = (const float*)d_in[3];
  const float* n2b   = (const float*)d_in[4];
  const float* qkvw  = (const float*)d_in[5];
  const float* projw = (const float*)d_in[6];
  const float* projb = (const float*)d_in[7];
  const float* f1w   = (const float*)d_in[8];
  const float* f1b   = (const float*)d_in[9];
  const float* f2w   = (const float*)d_in[10];
  const float* f2b   = (const float*)d_in[11];
  float* out = (float*)d_out;

  u16* ws  = (u16*)d_ws;
  u16* pkq = ws;                        // 3*65536 u16
  u16* pkp = pkq + 196608;              // 65536
  u16* pk1 = pkp + 65536;               // 4*65536
  u16* pk2 = pk1 + 262144;              // 32 ksteps -> 262144   (total 1.57 MB bf16)

  hipLaunchKernelGGL(wpack_kernel, dim3(384), dim3(256), 0, stream,
                     qkvw, projw, f1w, f2w, pkq, pkp, pk1, pk2);
  hipLaunchKernelGGL(swin_fused_kernel, dim3(2048), dim3(512), 0, stream,
                     x, n1w, n1b, n2w, n2b, pkq, pkp, projb, pk1, f1b, pk2, f2b, out);
}

// Round 6
// 626.646 us; speedup vs baseline: 1.7740x; 1.5092x over previous
//
#include <hip/hip_runtime.h>
#include <hip/hip_bf16.h>

#define C_ 256
#define L_ 16384
#define CL_ (C_*L_)

typedef unsigned int u32;
typedef unsigned short u16;
typedef __bf16 bf16_t;
typedef bf16_t bf16x8 __attribute__((ext_vector_type(8)));
typedef float f32x4 __attribute__((ext_vector_type(4)));

__device__ __forceinline__ float bf2f(u16 v){ return __builtin_bit_cast(float, ((u32)v)<<16); }
__device__ __forceinline__ u16 f2bf(float f){
  u32 u = __builtin_bit_cast(u32, f);
  u32 r = u + 0x7FFFu + ((u>>16)&1u);
  return (u16)(r>>16);
}
__device__ __forceinline__ u32 pack2(float a, float b){ return (u32)f2bf(a) | ((u32)f2bf(b)<<16); }

// ---------------- weight PACK kernel ----------------
// Packs fp32 W[k][n] into per-lane MFMA B-fragment order, bf16:
// frag(kstep,nt,lane) 16B = W^T[nt*16+(l&15)][kstep*32 + (l>>4)*8 .. +8)
// layout: pk[((kstep*16+nt)*64 + l)*8 u16]. One 256-col slice = 65536 u16 (128KB).
__global__ void wpack_kernel(const float* __restrict__ qkvw, const float* __restrict__ projw,
                             const float* __restrict__ f1w, const float* __restrict__ f2w,
                             u16* __restrict__ pq, u16* __restrict__ pp,
                             u16* __restrict__ p1, u16* __restrict__ p2)
{
  int bid = blockIdx.x, tid = threadIdx.x;
  const float* src; u16* dst; int stride, n, k;
  if (bid < 96){                       // qkv: 3 slices x 8 ksteps x 16 nt x 64 l
    int f = bid*256 + tid;
    int l = f & 63, nt = (f>>6) & 15, kk = f>>10;
    int s = kk>>3, ks = kk&7;
    stride = 768; src = qkvw;
    n = s*256 + nt*16 + (l&15);
    k = ks*32 + ((l>>4)<<3);
    dst = pq + (size_t)s*65536 + ((size_t)(ks*16 + nt)*64 + l)*8;
  } else if (bid < 128){               // proj: 8 ksteps
    int f = (bid-96)*256 + tid;
    int l = f & 63, nt = (f>>6) & 15, ks = f>>10;
    stride = 256; src = projw;
    n = nt*16 + (l&15);
    k = ks*32 + ((l>>4)<<3);
    dst = pp + ((size_t)(ks*16 + nt)*64 + l)*8;
  } else if (bid < 256){               // ff1: 4 slices x 8 ksteps
    int f = (bid-128)*256 + tid;
    int l = f & 63, nt = (f>>6) & 15, kk = f>>10;
    int c2 = kk>>3, ks = kk&7;
    stride = 1024; src = f1w;
    n = c2*256 + nt*16 + (l&15);
    k = ks*32 + ((l>>4)<<3);
    dst = p1 + (size_t)c2*65536 + ((size_t)(ks*16 + nt)*64 + l)*8;
  } else {                             // ff2: K=1024 -> 32 global ksteps
    int f = (bid-256)*256 + tid;
    int l = f & 63, nt = (f>>6) & 15, ks = f>>10;     // ks 0..31
    stride = 256; src = f2w;
    n = nt*16 + (l&15);
    k = ks*32 + ((l>>4)<<3);
    dst = p2 + ((size_t)(ks*16 + nt)*64 + l)*8;
  }
  u16 v[8];
  #pragma unroll
  for (int j = 0; j < 8; ++j) v[j] = f2bf(src[(size_t)(k+j)*stride + n]);
  uint4 o;
  o.x = (u32)v[0] | ((u32)v[1]<<16);
  o.y = (u32)v[2] | ((u32)v[3]<<16);
  o.z = (u32)v[4] | ((u32)v[5]<<16);
  o.w = (u32)v[6] | ((u32)v[7]<<16);
  *(uint4*)dst = o;
}

// ---------------- barrier-free GEMM: A from LDS, B direct global (packed) ----------------
// A tile layout: byte = t*512 + ((2k) ^ ((t&7)<<4)), t in [0,64), k in [0,256)
__device__ __forceinline__ void gemmP(const u16* Abase, const u16* __restrict__ pk,
                                      int l, int ntb, f32x4 acc[4][2])
{
  #pragma unroll
  for (int ks = 0; ks < 8; ++ks){
    bf16x8 b0 = *(const bf16x8*)(pk + ((size_t)(ks*16 + ntb    )*64 + l)*8);
    bf16x8 b1 = *(const bf16x8*)(pk + ((size_t)(ks*16 + ntb + 1)*64 + l)*8);
    int k0 = ks*32;
    bf16x8 a[4];
    #pragma unroll
    for (int m = 0; m < 4; ++m){
      int t = m*16 + (l & 15);
      int off = t*512 + ((2*(k0 + ((l>>4)<<3))) ^ ((t&7)<<4));
      a[m] = *(const bf16x8*)((const char*)Abase + off);
    }
    #pragma unroll
    for (int m = 0; m < 4; ++m){
      acc[m][0] = __builtin_amdgcn_mfma_f32_16x16x32_bf16(a[m], b0, acc[m][0], 0, 0, 0);
      acc[m][1] = __builtin_amdgcn_mfma_f32_16x16x32_bf16(a[m], b1, acc[m][1], 0, 0, 0);
    }
  }
}

#define ZERO_ACC(A) { _Pragma("unroll") for (int m_ = 0; m_ < 4; ++m_){ A[m_][0] = (f32x4){0,0,0,0}; A[m_][1] = (f32x4){0,0,0,0}; } }

// ---------------- fully fused block kernel ----------------
// block = 64 tokens (original positions (blk*64+4+t) mod L), 512 threads, ~68.5 KiB LDS
// launch_bounds(512,2): 2 blocks/CU -> 16 waves/CU -> VGPR cap 128 (no spills; live set ~100)
__launch_bounds__(512, 2)
__global__ void swin_fused_kernel(const float* __restrict__ x,
                                  const float* __restrict__ n1w, const float* __restrict__ n1b,
                                  const float* __restrict__ n2w, const float* __restrict__ n2b,
                                  const u16* __restrict__ pkq, const u16* __restrict__ pkp,
                                  const float* __restrict__ projb,
                                  const u16* __restrict__ pk1, const float* __restrict__ f1b,
                                  const u16* __restrict__ pk2, const float* __restrict__ f2b,
                                  float* __restrict__ out)
{
  __shared__ u16 smem[35072];            // 68.5 KiB -> 2 blocks/CU
  u16* Buf1 = smem;                      // 32K: A-ln1 -> raw dump -> A-ln2
  u16* Buf2 = smem + 16384;              // 32K: K -> Q -> V -> O -> xt1 -> H
  float* redF   = (float*)(smem + 32768);  // [2][8][64]
  float* statsF = redF + 1024;             // [64][2]

  const int tid = threadIdx.x;
  const int w = tid >> 6;
  const int l = tid & 63;
  const int bb = blockIdx.x >> 8;
  const int blkl = blockIdx.x & 255;
  const int l0 = blkl*64 + 4;
  const float* xb = x + (size_t)bb*CL_;
  const int ntb = w*2;

  // ---- phase 1: load x (8 consecutive channels x 4 tokens per thread), LN1 ----
  const int q4 = tid & 15, cg = tid >> 4;
  int lq = l0 + 4*q4; if (lq >= L_) lq -= L_;
  float4 xr[8];
  float s1[4] = {0.f,0.f,0.f,0.f};
  float s2[4] = {0.f,0.f,0.f,0.f};
  #pragma unroll
  for (int ci = 0; ci < 8; ++ci){
    int c = cg*8 + ci;
    float4 d = *(const float4*)(xb + (size_t)c*L_ + lq);
    xr[ci] = d;
    s1[0]+=d.x; s2[0]+=d.x*d.x;  s1[1]+=d.y; s2[1]+=d.y*d.y;
    s1[2]+=d.z; s2[2]+=d.z*d.z;  s1[3]+=d.w; s2[3]+=d.w*d.w;
  }
  #pragma unroll
  for (int off = 16; off < 64; off <<= 1){
    #pragma unroll
    for (int jj = 0; jj < 4; ++jj){
      s1[jj] += __shfl_xor(s1[jj], off);
      s2[jj] += __shfl_xor(s2[jj], off);
    }
  }
  if (l < 16){
    #pragma unroll
    for (int jj = 0; jj < 4; ++jj){
      redF[w*64 + 4*l + jj] = s1[jj];
      redF[512 + w*64 + 4*l + jj] = s2[jj];
    }
  }
  __syncthreads();
  if (tid < 64){
    float a = 0.f, b2 = 0.f;
    #pragma unroll
    for (int ww = 0; ww < 8; ++ww){ a += redF[ww*64 + tid]; b2 += redF[512 + ww*64 + tid]; }
    float mu = a * (1.f/256.f);
    float var = fmaxf(b2 * (1.f/256.f) - mu*mu, 0.f);
    statsF[2*tid] = mu;
    statsF[2*tid+1] = rsqrtf(var + 1e-5f);
  }
  __syncthreads();

  u32 praw[4][4];
  #pragma unroll
  for (int jj = 0; jj < 4; ++jj){
    int t = 4*q4 + jj;
    float mu = statsF[2*t], rs = statsF[2*t+1];
    u32 aw[4];
    #pragma unroll
    for (int cp = 0; cp < 4; ++cp){
      int c0c = cg*8 + 2*cp;
      float v0 = ((const float*)&xr[2*cp])[jj];
      float v1 = ((const float*)&xr[2*cp+1])[jj];
      aw[cp] = pack2((v0-mu)*rs*n1w[c0c] + n1b[c0c], (v1-mu)*rs*n1w[c0c+1] + n1b[c0c+1]);
      praw[jj][cp] = pack2(v0, v1);
    }
    *(uint4*)((char*)Buf1 + t*512 + ((cg*16) ^ ((t&7)<<4))) = make_uint4(aw[0],aw[1],aw[2],aw[3]);
  }
  __syncthreads();                       // A-ln1 ready

  // ---- K GEMM -> Buf2 ----
  {
    f32x4 acc[4][2]; ZERO_ACC(acc);
    gemmP(Buf1, pkq + 65536, l, ntb, acc);
    #pragma unroll
    for (int m = 0; m < 4; ++m)
      #pragma unroll
      for (int n2 = 0; n2 < 2; ++n2)
        #pragma unroll
        for (int jj = 0; jj < 4; ++jj){
          int t = m*16 + ((l>>4)<<2) + jj;
          int c = (w<<5) + (n2<<4) + (l&15);
          *(u16*)((char*)Buf2 + t*512 + ((2*c) ^ ((t&7)<<4))) = f2bf(acc[m][n2][jj]);
        }
  }
  __syncthreads();

  // ---- read kr packed (held through Q GEMM: 16 regs) ----
  const int hh = (tid >> 3) & 7, rr = tid & 7;
  const int tq = w*8 + rr;
  u32 kr[16];
  #pragma unroll
  for (int g = 0; g < 4; ++g){
    uint4 dk = *(const uint4*)((char*)Buf2 + tq*512 + ((hh*64 + 16*g) ^ ((tq&7)<<4)));
    kr[g*4+0] = dk.x; kr[g*4+1] = dk.y; kr[g*4+2] = dk.z; kr[g*4+3] = dk.w;
  }
  __syncthreads();                       // kr reads done before Q-epi overwrite

  // ---- Q GEMM -> Buf2 ----
  {
    f32x4 acc[4][2]; ZERO_ACC(acc);
    gemmP(Buf1, pkq, l, ntb, acc);
    #pragma unroll
    for (int m = 0; m < 4; ++m)
      #pragma unroll
      for (int n2 = 0; n2 < 2; ++n2)
        #pragma unroll
        for (int jj = 0; jj < 4; ++jj){
          int t = m*16 + ((l>>4)<<2) + jj;
          int c = (w<<5) + (n2<<4) + (l&15);
          *(u16*)((char*)Buf2 + t*512 + ((2*c) ^ ((t&7)<<4))) = f2bf(acc[m][n2][jj]);
        }
  }
  __syncthreads();

  // ---- scores + softmax (qf transient; pr kept in regs) ----
  float pr[8];
  {
    float qf[32];
    #pragma unroll
    for (int g = 0; g < 4; ++g){
      uint4 dq = *(const uint4*)((char*)Buf2 + tq*512 + ((hh*64 + 16*g) ^ ((tq&7)<<4)));
      qf[g*8+0] = bf2f((u16)dq.x); qf[g*8+1] = bf2f((u16)(dq.x>>16));
      qf[g*8+2] = bf2f((u16)dq.y); qf[g*8+3] = bf2f((u16)(dq.y>>16));
      qf[g*8+4] = bf2f((u16)dq.z); qf[g*8+5] = bf2f((u16)(dq.z>>16));
      qf[g*8+6] = bf2f((u16)dq.w); qf[g*8+7] = bf2f((u16)(dq.w>>16));
    }
    float s[8];
    #pragma unroll
    for (int j = 0; j < 8; ++j){
      float dot = 0.f;
      #pragma unroll
      for (int reg = 0; reg < 16; ++reg){
        u32 kj = (u32)__shfl((int)kr[reg], j, 8);
        dot += qf[2*reg]   * bf2f((u16)kj);
        dot += qf[2*reg+1] * bf2f((u16)(kj>>16));
      }
      s[j] = dot * 0.17677669529663687f;
    }
    float mx = s[0];
    #pragma unroll
    for (int j = 1; j < 8; ++j) mx = fmaxf(mx, s[j]);
    float sum = 0.f;
    #pragma unroll
    for (int j = 0; j < 8; ++j){ pr[j] = __expf(s[j]-mx); sum += pr[j]; }
    float inv = 1.0f / sum;
    #pragma unroll
    for (int j = 0; j < 8; ++j) pr[j] *= inv;
  }
  __syncthreads();                       // Q reads done before V-epi overwrite

  // ---- V GEMM -> Buf2; then raw dump -> Buf1 ----
  {
    f32x4 acc[4][2]; ZERO_ACC(acc);
    gemmP(Buf1, pkq + 131072, l, ntb, acc);
    __syncthreads();                     // all Buf1 A-frag reads done
    #pragma unroll
    for (int m = 0; m < 4; ++m)
      #pragma unroll
      for (int n2 = 0; n2 < 2; ++n2)
        #pragma unroll
        for (int jj = 0; jj < 4; ++jj){
          int t = m*16 + ((l>>4)<<2) + jj;
          int c = (w<<5) + (n2<<4) + (l&15);
          *(u16*)((char*)Buf2 + t*512 + ((2*c) ^ ((t&7)<<4))) = f2bf(acc[m][n2][jj]);
        }
    #pragma unroll
    for (int jj = 0; jj < 4; ++jj){
      int t = 4*q4 + jj;
      *(uint4*)((char*)Buf1 + t*512 + ((cg*16) ^ ((t&7)<<4))) =
          make_uint4(praw[jj][0], praw[jj][1], praw[jj][2], praw[jj][3]);
    }
  }
  __syncthreads();

  // ---- PV: read V rows, write O in place (per-thread disjoint) ----
  {
    u32 vr[16];
    #pragma unroll
    for (int g = 0; g < 4; ++g){
      uint4 dv = *(const uint4*)((char*)Buf2 + tq*512 + ((hh*64 + 16*g) ^ ((tq&7)<<4)));
      vr[g*4+0] = dv.x; vr[g*4+1] = dv.y; vr[g*4+2] = dv.z; vr[g*4+3] = dv.w;
    }
    float of[32];
    #pragma unroll
    for (int d = 0; d < 32; ++d) of[d] = 0.f;
    #pragma unroll
    for (int j = 0; j < 8; ++j){
      float pj = pr[j];
      #pragma unroll
      for (int reg = 0; reg < 16; ++reg){
        u32 vj = (u32)__shfl((int)vr[reg], j, 8);
        of[2*reg]   += pj*bf2f((u16)vj);
        of[2*reg+1] += pj*bf2f((u16)(vj>>16));
      }
    }
    #pragma unroll
    for (int g = 0; g < 4; ++g){
      uint4 o;
      o.x = pack2(of[g*8+0], of[g*8+1]);
      o.y = pack2(of[g*8+2], of[g*8+3]);
      o.z = pack2(of[g*8+4], of[g*8+5]);
      o.w = pack2(of[g*8+6], of[g*8+7]);
      *(uint4*)((char*)Buf2 + tq*512 + ((hh*64 + 16*g) ^ ((tq&7)<<4))) = o;
    }
  }
  __syncthreads();

  // ---- proj GEMM (A=Buf2=O) ----
  u32 xt1p[4][2][2];
  {
    f32x4 acc[4][2]; ZERO_ACC(acc);
    gemmP(Buf2, pkp, l, ntb, acc);
    __syncthreads();                     // all Buf2 O-reads done
    #pragma unroll
    for (int m = 0; m < 4; ++m)
      #pragma unroll
      for (int n2 = 0; n2 < 2; ++n2){
        float vv[4];
        #pragma unroll
        for (int jj = 0; jj < 4; ++jj){
          int t = m*16 + ((l>>4)<<2) + jj;
          int c = (w<<5) + (n2<<4) + (l&15);
          float rv = bf2f(*(const u16*)((char*)Buf1 + t*512 + ((2*c) ^ ((t&7)<<4))));
          float v = acc[m][n2][jj] + projb[c] + rv;
          vv[jj] = v;
          *(u16*)((char*)Buf2 + t*512 + 2*c) = f2bf(v);   // xt1 tile, linear
        }
        xt1p[m][n2][0] = pack2(vv[0], vv[1]);
        xt1p[m][n2][1] = pack2(vv[2], vv[3]);
      }
  }
  __syncthreads();

  // ---- LN2 (read Buf2 linear, write Buf1 swizzled) ----
  {
    float4 wv = *(const float4*)(n2w + 4*l);
    float4 bv = *(const float4*)(n2b + 4*l);
    #pragma unroll 1
    for (int r = 0; r < 8; ++r){
      int t = w*8 + r;
      uint2 d = *(const uint2*)((char*)Buf2 + t*512 + 8*l);
      float f0 = bf2f((u16)d.x), f1 = bf2f((u16)(d.x>>16));
      float f2 = bf2f((u16)d.y), f3 = bf2f((u16)(d.y>>16));
      float ls1 = f0+f1+f2+f3;
      float ls2 = f0*f0+f1*f1+f2*f2+f3*f3;
      #pragma unroll
      for (int off = 1; off < 64; off <<= 1){
        ls1 += __shfl_xor(ls1, off);
        ls2 += __shfl_xor(ls2, off);
      }
      float mu = ls1 * (1.f/256.f);
      float var = fmaxf(ls2 * (1.f/256.f) - mu*mu, 0.f);
      float rs = rsqrtf(var + 1e-5f);
      uint2 pp;
      pp.x = pack2((f0-mu)*rs*wv.x+bv.x, (f1-mu)*rs*wv.y+bv.y);
      pp.y = pack2((f2-mu)*rs*wv.z+bv.z, (f3-mu)*rs*wv.w+bv.w);
      *(uint2*)((char*)Buf1 + t*512 + ((8*l) ^ ((t&7)<<4))) = pp;
    }
  }
  __syncthreads();                       // A-ln2 ready

  // ---- FF: 4 hidden chunks of 256; H in Buf2 ----
  f32x4 acc2[4][2]; ZERO_ACC(acc2);
  #pragma unroll 1
  for (int c2 = 0; c2 < 4; ++c2){
    f32x4 acc1[4][2]; ZERO_ACC(acc1);
    gemmP(Buf1, pk1 + (size_t)c2*65536, l, ntb, acc1);
    __syncthreads();                     // prior Buf2 readers done
    #pragma unroll
    for (int m = 0; m < 4; ++m)
      #pragma unroll
      for (int n2 = 0; n2 < 2; ++n2)
        #pragma unroll
        for (int jj = 0; jj < 4; ++jj){
          int t = m*16 + ((l>>4)<<2) + jj;
          int c = (w<<5) + (n2<<4) + (l&15);
          float xv = acc1[m][n2][jj] + f1b[c2*256 + c];
          float g = 0.5f*xv*(1.f + erff(xv*0.70710678118654752f));
          *(u16*)((char*)Buf2 + t*512 + ((2*c) ^ ((t&7)<<4))) = f2bf(g);
        }
    __syncthreads();                     // H ready
    gemmP(Buf2, pk2 + (size_t)c2*65536, l, ntb, acc2);
    __syncthreads();                     // H reads done (guards next gelu-epi / OutF)
  }

  // ---- final epilogue: +f2b +xt1(regs) -> fp32 stage across Buf1+Buf2 ----
  float* OutF = (float*)smem;            // [c 0..255][t 0..63] fp32, 16B-XOR swizzled
  #pragma unroll
  for (int m = 0; m < 4; ++m)
    #pragma unroll
    for (int n2 = 0; n2 < 2; ++n2)
      #pragma unroll
      for (int jj = 0; jj < 4; ++jj){
        int t = m*16 + ((l>>4)<<2) + jj;
        int c = (w<<5) + (n2<<4) + (l&15);
        u32 p = xt1p[m][n2][jj>>1];
        float rv = bf2f((u16)((jj&1) ? (p>>16) : (p&0xFFFF)));
        float v = acc2[m][n2][jj] + f2b[c] + rv;
        *(float*)((char*)OutF + c*256 + ((4*t) ^ ((c&15)<<4))) = v;
      }
  __syncthreads();

  // ---- transposed global write out[b][c][(l0+4qd..) mod L] ----
  float* ob = out + (size_t)bb*CL_;
  #pragma unroll
  for (int ii = 0; ii < 8; ++ii){
    int id = tid + ii*512;
    int c = id >> 4, qd = id & 15;
    int lw = l0 + 4*qd; if (lw >= L_) lw -= L_;
    float4 vv = *(const float4*)((char*)OutF + c*256 + ((16*qd) ^ ((c&15)<<4)));
    *(float4*)(ob + (size_t)c*L_ + lw) = vv;
  }
}

// ---------------- launch ----------------
extern "C" void kernel_launch(void* const* d_in, const int* in_sizes, int n_in,
                              void* d_out, int out_size, void* d_ws, size_t ws_size,
                              hipStream_t stream)
{
  const float* x     = (const float*)d_in[0];
  const float* n1w   = (const float*)d_in[1];
  const float* n1b   = (const float*)d_in[2];
  const float* n2w   = (const float*)d_in[3];
  const float* n2b   = (const float*)d_in[4];
  const float* qkvw  = (const float*)d_in[5];
  const float* projw = (const float*)d_in[6];
  const float* projb = (const float*)d_in[7];
  const float* f1w   = (const float*)d_in[8];
  const float* f1b   = (const float*)d_in[9];
  const float* f2w   = (const float*)d_in[10];
  const float* f2b   = (const float*)d_in[11];
  float* out = (float*)d_out;

  u16* ws  = (u16*)d_ws;
  u16* pkq = ws;                        // 3*65536 u16
  u16* pkp = pkq + 196608;              // 65536
  u16* pk1 = pkp + 65536;               // 4*65536
  u16* pk2 = pk1 + 262144;              // 32 ksteps -> 262144   (total 1.57 MB bf16)

  hipLaunchKernelGGL(wpack_kernel, dim3(384), dim3(256), 0, stream,
                     qkvw, projw, f1w, f2w, pkq, pkp, pk1, pk2);
  hipLaunchKernelGGL(swin_fused_kernel, dim3(2048), dim3(512), 0, stream,
                     x, n1w, n1b, n2w, n2b, pkq, pkp, projb, pk1, f1b, pk2, f2b, out);
}

// Round 7
// 600.133 us; speedup vs baseline: 1.8524x; 1.0442x over previous
//
#include <hip/hip_runtime.h>
#include <hip/hip_bf16.h>

#define C_ 256
#define L_ 16384
#define CL_ (C_*L_)

typedef unsigned int u32;
typedef unsigned short u16;
typedef __bf16 bf16_t;
typedef bf16_t bf16x8 __attribute__((ext_vector_type(8)));
typedef float f32x4 __attribute__((ext_vector_type(4)));

__device__ __forceinline__ float bf2f(u16 v){ return __builtin_bit_cast(float, ((u32)v)<<16); }
__device__ __forceinline__ u16 f2bf(float f){
  u32 u = __builtin_bit_cast(u32, f);
  u32 r = u + 0x7FFFu + ((u>>16)&1u);
  return (u16)(r>>16);
}
__device__ __forceinline__ u32 pack2(float a, float b){ return (u32)f2bf(a) | ((u32)f2bf(b)<<16); }

// ---------------- weight PACK kernel ----------------
// Packs fp32 W[k][n] into per-lane MFMA B-fragment order, bf16:
// frag(kstep,nt,lane) 16B = W^T[nt*16+(l&15)][kstep*32 + (l>>4)*8 .. +8)
__global__ void wpack_kernel(const float* __restrict__ qkvw, const float* __restrict__ projw,
                             const float* __restrict__ f1w, const float* __restrict__ f2w,
                             u16* __restrict__ pq, u16* __restrict__ pp,
                             u16* __restrict__ p1, u16* __restrict__ p2)
{
  int bid = blockIdx.x, tid = threadIdx.x;
  const float* src; u16* dst; int stride, n, k;
  if (bid < 96){
    int f = bid*256 + tid;
    int l = f & 63, nt = (f>>6) & 15, kk = f>>10;
    int s = kk>>3, ks = kk&7;
    stride = 768; src = qkvw;
    n = s*256 + nt*16 + (l&15);
    k = ks*32 + ((l>>4)<<3);
    dst = pq + (size_t)s*65536 + ((size_t)(ks*16 + nt)*64 + l)*8;
  } else if (bid < 128){
    int f = (bid-96)*256 + tid;
    int l = f & 63, nt = (f>>6) & 15, ks = f>>10;
    stride = 256; src = projw;
    n = nt*16 + (l&15);
    k = ks*32 + ((l>>4)<<3);
    dst = pp + ((size_t)(ks*16 + nt)*64 + l)*8;
  } else if (bid < 256){
    int f = (bid-128)*256 + tid;
    int l = f & 63, nt = (f>>6) & 15, kk = f>>10;
    int c2 = kk>>3, ks = kk&7;
    stride = 1024; src = f1w;
    n = c2*256 + nt*16 + (l&15);
    k = ks*32 + ((l>>4)<<3);
    dst = p1 + (size_t)c2*65536 + ((size_t)(ks*16 + nt)*64 + l)*8;
  } else {
    int f = (bid-256)*256 + tid;
    int l = f & 63, nt = (f>>6) & 15, ks = f>>10;
    stride = 256; src = f2w;
    n = nt*16 + (l&15);
    k = ks*32 + ((l>>4)<<3);
    dst = p2 + ((size_t)(ks*16 + nt)*64 + l)*8;
  }
  u16 v[8];
  #pragma unroll
  for (int j = 0; j < 8; ++j) v[j] = f2bf(src[(size_t)(k+j)*stride + n]);
  uint4 o;
  o.x = (u32)v[0] | ((u32)v[1]<<16);
  o.y = (u32)v[2] | ((u32)v[3]<<16);
  o.z = (u32)v[4] | ((u32)v[5]<<16);
  o.w = (u32)v[6] | ((u32)v[7]<<16);
  *(uint4*)dst = o;
}

// ---------------- barrier-free GEMM: A from LDS, B direct global (packed) ----------------
// A tile layout: byte = t*512 + ((2k) ^ ((t&7)<<4)), t in [0,64), k in [0,256)
__device__ __forceinline__ void gemmP(const u16* Abase, const u16* __restrict__ pk,
                                      int l, int ntb, f32x4 acc[4][2])
{
  #pragma unroll
  for (int ks = 0; ks < 8; ++ks){
    bf16x8 b0 = *(const bf16x8*)(pk + ((size_t)(ks*16 + ntb    )*64 + l)*8);
    bf16x8 b1 = *(const bf16x8*)(pk + ((size_t)(ks*16 + ntb + 1)*64 + l)*8);
    int k0 = ks*32;
    bf16x8 a[4];
    #pragma unroll
    for (int m = 0; m < 4; ++m){
      int t = m*16 + (l & 15);
      int off = t*512 + ((2*(k0 + ((l>>4)<<3))) ^ ((t&7)<<4));
      a[m] = *(const bf16x8*)((const char*)Abase + off);
    }
    #pragma unroll
    for (int m = 0; m < 4; ++m){
      acc[m][0] = __builtin_amdgcn_mfma_f32_16x16x32_bf16(a[m], b0, acc[m][0], 0, 0, 0);
      acc[m][1] = __builtin_amdgcn_mfma_f32_16x16x32_bf16(a[m], b1, acc[m][1], 0, 0, 0);
    }
  }
}

#define ZERO_ACC(A) { _Pragma("unroll") for (int m_ = 0; m_ < 4; ++m_){ A[m_][0] = (f32x4){0,0,0,0}; A[m_][1] = (f32x4){0,0,0,0}; } }

// ================= kernel 1: LN1 + window attention + proj + residual =================
// writes xt1 (bf16, channel-major [b][c][l]) and per-token LN2 stats (mu, rs)
__launch_bounds__(512, 2)
__global__ void swin_attn_kernel(const float* __restrict__ x,
                                 const float* __restrict__ n1w, const float* __restrict__ n1b,
                                 const u16* __restrict__ pkq, const u16* __restrict__ pkp,
                                 const float* __restrict__ projb,
                                 u16* __restrict__ xt1g, float* __restrict__ statsg)
{
  __shared__ u16 smem[35072];
  u16* Buf1 = smem;                        // A-ln1 -> raw dump
  u16* Buf2 = smem + 16384;                // K -> Q -> V -> O -> xt1 (c-major)
  float* redF   = (float*)(smem + 32768);  // [2][8][64]
  float* statsF = redF + 1024;             // [64][2]

  const int tid = threadIdx.x;
  const int w = tid >> 6;
  const int l = tid & 63;
  const int bb = blockIdx.x >> 8;
  const int blkl = blockIdx.x & 255;
  const int l0 = blkl*64 + 4;
  const float* xb = x + (size_t)bb*CL_;
  const int ntb = w*2;

  // ---- LN1 ----
  const int q4 = tid & 15, cg = tid >> 4;
  int lq = l0 + 4*q4; if (lq >= L_) lq -= L_;
  float4 xr[8];
  float s1[4] = {0.f,0.f,0.f,0.f};
  float s2[4] = {0.f,0.f,0.f,0.f};
  #pragma unroll
  for (int ci = 0; ci < 8; ++ci){
    int c = cg*8 + ci;
    float4 d = *(const float4*)(xb + (size_t)c*L_ + lq);
    xr[ci] = d;
    s1[0]+=d.x; s2[0]+=d.x*d.x;  s1[1]+=d.y; s2[1]+=d.y*d.y;
    s1[2]+=d.z; s2[2]+=d.z*d.z;  s1[3]+=d.w; s2[3]+=d.w*d.w;
  }
  #pragma unroll
  for (int off = 16; off < 64; off <<= 1){
    #pragma unroll
    for (int jj = 0; jj < 4; ++jj){
      s1[jj] += __shfl_xor(s1[jj], off);
      s2[jj] += __shfl_xor(s2[jj], off);
    }
  }
  if (l < 16){
    #pragma unroll
    for (int jj = 0; jj < 4; ++jj){
      redF[w*64 + 4*l + jj] = s1[jj];
      redF[512 + w*64 + 4*l + jj] = s2[jj];
    }
  }
  __syncthreads();
  if (tid < 64){
    float a = 0.f, b2 = 0.f;
    #pragma unroll
    for (int ww = 0; ww < 8; ++ww){ a += redF[ww*64 + tid]; b2 += redF[512 + ww*64 + tid]; }
    float mu = a * (1.f/256.f);
    float var = fmaxf(b2 * (1.f/256.f) - mu*mu, 0.f);
    statsF[2*tid] = mu;
    statsF[2*tid+1] = rsqrtf(var + 1e-5f);
  }
  __syncthreads();

  u32 praw[4][4];
  #pragma unroll
  for (int jj = 0; jj < 4; ++jj){
    int t = 4*q4 + jj;
    float mu = statsF[2*t], rs = statsF[2*t+1];
    u32 aw[4];
    #pragma unroll
    for (int cp = 0; cp < 4; ++cp){
      int c0c = cg*8 + 2*cp;
      float v0 = ((const float*)&xr[2*cp])[jj];
      float v1 = ((const float*)&xr[2*cp+1])[jj];
      aw[cp] = pack2((v0-mu)*rs*n1w[c0c] + n1b[c0c], (v1-mu)*rs*n1w[c0c+1] + n1b[c0c+1]);
      praw[jj][cp] = pack2(v0, v1);
    }
    *(uint4*)((char*)Buf1 + t*512 + ((cg*16) ^ ((t&7)<<4))) = make_uint4(aw[0],aw[1],aw[2],aw[3]);
  }
  __syncthreads();

  // ---- K GEMM -> Buf2 ----
  {
    f32x4 acc[4][2]; ZERO_ACC(acc);
    gemmP(Buf1, pkq + 65536, l, ntb, acc);
    #pragma unroll
    for (int m = 0; m < 4; ++m)
      #pragma unroll
      for (int n2 = 0; n2 < 2; ++n2)
        #pragma unroll
        for (int jj = 0; jj < 4; ++jj){
          int t = m*16 + ((l>>4)<<2) + jj;
          int c = (w<<5) + (n2<<4) + (l&15);
          *(u16*)((char*)Buf2 + t*512 + ((2*c) ^ ((t&7)<<4))) = f2bf(acc[m][n2][jj]);
        }
  }
  __syncthreads();

  const int hh = (tid >> 3) & 7, rr = tid & 7;
  const int tq = w*8 + rr;
  u32 kr[16];
  #pragma unroll
  for (int g = 0; g < 4; ++g){
    uint4 dk = *(const uint4*)((char*)Buf2 + tq*512 + ((hh*64 + 16*g) ^ ((tq&7)<<4)));
    kr[g*4+0] = dk.x; kr[g*4+1] = dk.y; kr[g*4+2] = dk.z; kr[g*4+3] = dk.w;
  }
  __syncthreads();

  // ---- Q GEMM -> Buf2 ----
  {
    f32x4 acc[4][2]; ZERO_ACC(acc);
    gemmP(Buf1, pkq, l, ntb, acc);
    #pragma unroll
    for (int m = 0; m < 4; ++m)
      #pragma unroll
      for (int n2 = 0; n2 < 2; ++n2)
        #pragma unroll
        for (int jj = 0; jj < 4; ++jj){
          int t = m*16 + ((l>>4)<<2) + jj;
          int c = (w<<5) + (n2<<4) + (l&15);
          *(u16*)((char*)Buf2 + t*512 + ((2*c) ^ ((t&7)<<4))) = f2bf(acc[m][n2][jj]);
        }
  }
  __syncthreads();

  // ---- scores + softmax ----
  float pr[8];
  {
    float qf[32];
    #pragma unroll
    for (int g = 0; g < 4; ++g){
      uint4 dq = *(const uint4*)((char*)Buf2 + tq*512 + ((hh*64 + 16*g) ^ ((tq&7)<<4)));
      qf[g*8+0] = bf2f((u16)dq.x); qf[g*8+1] = bf2f((u16)(dq.x>>16));
      qf[g*8+2] = bf2f((u16)dq.y); qf[g*8+3] = bf2f((u16)(dq.y>>16));
      qf[g*8+4] = bf2f((u16)dq.z); qf[g*8+5] = bf2f((u16)(dq.z>>16));
      qf[g*8+6] = bf2f((u16)dq.w); qf[g*8+7] = bf2f((u16)(dq.w>>16));
    }
    float s[8];
    #pragma unroll
    for (int j = 0; j < 8; ++j){
      float dot = 0.f;
      #pragma unroll
      for (int reg = 0; reg < 16; ++reg){
        u32 kj = (u32)__shfl((int)kr[reg], j, 8);
        dot += qf[2*reg]   * bf2f((u16)kj);
        dot += qf[2*reg+1] * bf2f((u16)(kj>>16));
      }
      s[j] = dot * 0.17677669529663687f;
    }
    float mx = s[0];
    #pragma unroll
    for (int j = 1; j < 8; ++j) mx = fmaxf(mx, s[j]);
    float sum = 0.f;
    #pragma unroll
    for (int j = 0; j < 8; ++j){ pr[j] = __expf(s[j]-mx); sum += pr[j]; }
    float inv = 1.0f / sum;
    #pragma unroll
    for (int j = 0; j < 8; ++j) pr[j] *= inv;
  }
  __syncthreads();

  // ---- V GEMM -> Buf2; raw dump -> Buf1 ----
  {
    f32x4 acc[4][2]; ZERO_ACC(acc);
    gemmP(Buf1, pkq + 131072, l, ntb, acc);
    __syncthreads();
    #pragma unroll
    for (int m = 0; m < 4; ++m)
      #pragma unroll
      for (int n2 = 0; n2 < 2; ++n2)
        #pragma unroll
        for (int jj = 0; jj < 4; ++jj){
          int t = m*16 + ((l>>4)<<2) + jj;
          int c = (w<<5) + (n2<<4) + (l&15);
          *(u16*)((char*)Buf2 + t*512 + ((2*c) ^ ((t&7)<<4))) = f2bf(acc[m][n2][jj]);
        }
    #pragma unroll
    for (int jj = 0; jj < 4; ++jj){
      int t = 4*q4 + jj;
      *(uint4*)((char*)Buf1 + t*512 + ((cg*16) ^ ((t&7)<<4))) =
          make_uint4(praw[jj][0], praw[jj][1], praw[jj][2], praw[jj][3]);
    }
  }
  __syncthreads();

  // ---- PV ----
  {
    u32 vr[16];
    #pragma unroll
    for (int g = 0; g < 4; ++g){
      uint4 dv = *(const uint4*)((char*)Buf2 + tq*512 + ((hh*64 + 16*g) ^ ((tq&7)<<4)));
      vr[g*4+0] = dv.x; vr[g*4+1] = dv.y; vr[g*4+2] = dv.z; vr[g*4+3] = dv.w;
    }
    float of[32];
    #pragma unroll
    for (int d = 0; d < 32; ++d) of[d] = 0.f;
    #pragma unroll
    for (int j = 0; j < 8; ++j){
      float pj = pr[j];
      #pragma unroll
      for (int reg = 0; reg < 16; ++reg){
        u32 vj = (u32)__shfl((int)vr[reg], j, 8);
        of[2*reg]   += pj*bf2f((u16)vj);
        of[2*reg+1] += pj*bf2f((u16)(vj>>16));
      }
    }
    #pragma unroll
    for (int g = 0; g < 4; ++g){
      uint4 o;
      o.x = pack2(of[g*8+0], of[g*8+1]);
      o.y = pack2(of[g*8+2], of[g*8+3]);
      o.z = pack2(of[g*8+4], of[g*8+5]);
      o.w = pack2(of[g*8+6], of[g*8+7]);
      *(uint4*)((char*)Buf2 + tq*512 + ((hh*64 + 16*g) ^ ((tq&7)<<4))) = o;
    }
  }
  __syncthreads();

  // ---- proj GEMM (A=Buf2=O); epi -> Buf2 c-major xt1 tile ----
  {
    f32x4 acc[4][2]; ZERO_ACC(acc);
    gemmP(Buf2, pkp, l, ntb, acc);
    __syncthreads();                     // all O-reads done
    #pragma unroll
    for (int m = 0; m < 4; ++m)
      #pragma unroll
      for (int n2 = 0; n2 < 2; ++n2)
        #pragma unroll
        for (int jj = 0; jj < 4; ++jj){
          int t = m*16 + ((l>>4)<<2) + jj;
          int c = (w<<5) + (n2<<4) + (l&15);
          float rv = bf2f(*(const u16*)((char*)Buf1 + t*512 + ((2*c) ^ ((t&7)<<4))));
          float v = acc[m][n2][jj] + projb[c] + rv;
          *(u16*)((char*)Buf2 + c*128 + ((2*t) ^ ((c&7)<<4))) = f2bf(v);
        }
  }
  __syncthreads();

  // ---- LN2 stats partials + xt1 global write (Buf2 stable) ----
  {
    float a = 0.f, b2 = 0.f;
    #pragma unroll
    for (int ci = 0; ci < 32; ++ci){
      int c = (w<<5) + ci;
      float v = bf2f(*(const u16*)((char*)Buf2 + c*128 + ((2*l) ^ ((c&7)<<4))));
      a += v; b2 += v*v;
    }
    redF[w*64 + l] = a;
    redF[512 + w*64 + l] = b2;
  }
  u16* xo = xt1g + (size_t)bb*CL_;
  #pragma unroll
  for (int ii = 0; ii < 8; ++ii){
    int id = tid + ii*512;
    int c = id >> 4, qd = id & 15;
    int lw = l0 + 4*qd; if (lw >= L_) lw -= L_;
    uint2 dd = *(const uint2*)((char*)Buf2 + c*128 + ((8*qd) ^ ((c&7)<<4)));
    *(uint2*)(xo + (size_t)c*L_ + lw) = dd;
  }
  __syncthreads();
  if (tid < 64){
    float a = 0.f, b2 = 0.f;
    #pragma unroll
    for (int ww = 0; ww < 8; ++ww){ a += redF[ww*64 + tid]; b2 += redF[512 + ww*64 + tid]; }
    float mu = a * (1.f/256.f);
    float var = fmaxf(b2 * (1.f/256.f) - mu*mu, 0.f);
    float2 st; st.x = mu; st.y = rsqrtf(var + 1e-5f);
    *(float2*)(statsg + (size_t)(bb*16384 + blkl*64 + tid)*2) = st;
  }
}

// ================= kernel 2: LN2-normalize + FF + residual + out =================
__launch_bounds__(512, 2)
__global__ void swin_ff_kernel(const u16* __restrict__ xt1g, const float* __restrict__ statsg,
                               const float* __restrict__ n2w, const float* __restrict__ n2b,
                               const u16* __restrict__ pk1, const float* __restrict__ f1b,
                               const u16* __restrict__ pk2, const float* __restrict__ f2b,
                               float* __restrict__ out)
{
  __shared__ u16 smem[32768];            // 64 KiB
  u16* Buf1 = smem;                      // A-ln2 tile
  u16* Buf2 = smem + 16384;              // H chunk

  const int tid = threadIdx.x;
  const int w = tid >> 6;
  const int l = tid & 63;
  const int bb = blockIdx.x >> 8;
  const int blkl = blockIdx.x & 255;
  const int l0 = blkl*64 + 4;
  const int ntb = w*2;
  const u16* xi = xt1g + (size_t)bb*CL_;

  // ---- load xt1 (c-major) + normalize -> A-ln2 tile ----
  const int q4 = tid & 15, cg = tid >> 4;
  int lq = l0 + 4*q4; if (lq >= L_) lq -= L_;
  u32 xl[8][2];
  #pragma unroll
  for (int ci = 0; ci < 8; ++ci){
    int c = cg*8 + ci;
    uint2 dd = *(const uint2*)(xi + (size_t)c*L_ + lq);
    xl[ci][0] = dd.x; xl[ci][1] = dd.y;
  }
  #pragma unroll
  for (int jj = 0; jj < 4; ++jj){
    int t = 4*q4 + jj;
    float2 st = *(const float2*)(statsg + (size_t)(bb*16384 + blkl*64 + t)*2);
    float mu = st.x, rs = st.y;
    u32 aw[4];
    #pragma unroll
    for (int cp = 0; cp < 4; ++cp){
      int c0c = cg*8 + 2*cp;
      float v0 = bf2f((u16)(xl[2*cp  ][jj>>1] >> (16*(jj&1))));
      float v1 = bf2f((u16)(xl[2*cp+1][jj>>1] >> (16*(jj&1))));
      aw[cp] = pack2((v0-mu)*rs*n2w[c0c] + n2b[c0c], (v1-mu)*rs*n2w[c0c+1] + n2b[c0c+1]);
    }
    *(uint4*)((char*)Buf1 + t*512 + ((cg*16) ^ ((t&7)<<4))) = make_uint4(aw[0],aw[1],aw[2],aw[3]);
  }
  __syncthreads();

  // ---- FF: 4 hidden chunks of 256 ----
  f32x4 acc2[4][2]; ZERO_ACC(acc2);
  #pragma unroll 1
  for (int c2 = 0; c2 < 4; ++c2){
    f32x4 acc1[4][2]; ZERO_ACC(acc1);
    gemmP(Buf1, pk1 + (size_t)c2*65536, l, ntb, acc1);
    __syncthreads();                     // prev gemm2's Buf2 reads done
    #pragma unroll
    for (int m = 0; m < 4; ++m)
      #pragma unroll
      for (int n2 = 0; n2 < 2; ++n2)
        #pragma unroll
        for (int jj = 0; jj < 4; ++jj){
          int t = m*16 + ((l>>4)<<2) + jj;
          int c = (w<<5) + (n2<<4) + (l&15);
          float xv = acc1[m][n2][jj] + f1b[c2*256 + c];
          float g = 0.5f*xv*(1.f + erff(xv*0.70710678118654752f));
          *(u16*)((char*)Buf2 + t*512 + ((2*c) ^ ((t&7)<<4))) = f2bf(g);
        }
    __syncthreads();                     // H ready
    gemmP(Buf2, pk2 + (size_t)c2*65536, l, ntb, acc2);
  }
  __syncthreads();                       // all LDS reads done

  // ---- epilogue: +f2b -> fp32 stage (c-major), then +residual on store ----
  float* OutF = (float*)smem;            // [c][t] fp32, 16B-XOR swizzled (64 KiB)
  #pragma unroll
  for (int m = 0; m < 4; ++m)
    #pragma unroll
    for (int n2 = 0; n2 < 2; ++n2)
      #pragma unroll
      for (int jj = 0; jj < 4; ++jj){
        int t = m*16 + ((l>>4)<<2) + jj;
        int c = (w<<5) + (n2<<4) + (l&15);
        float v = acc2[m][n2][jj] + f2b[c];
        *(float*)((char*)OutF + c*256 + ((4*t) ^ ((c&15)<<4))) = v;
      }
  __syncthreads();

  float* ob = out + (size_t)bb*CL_;
  #pragma unroll
  for (int ii = 0; ii < 8; ++ii){
    int id = tid + ii*512;
    int c = id >> 4, qd = id & 15;
    int lw = l0 + 4*qd; if (lw >= L_) lw -= L_;
    float4 vv = *(const float4*)((char*)OutF + c*256 + ((16*qd) ^ ((c&15)<<4)));
    uint2 rr = *(const uint2*)(xi + (size_t)c*L_ + lw);   // L3-hot residual
    vv.x += bf2f((u16)rr.x);  vv.y += bf2f((u16)(rr.x>>16));
    vv.z += bf2f((u16)rr.y);  vv.w += bf2f((u16)(rr.y>>16));
    *(float4*)(ob + (size_t)c*L_ + lw) = vv;
  }
}

// ================= fallback: round-6 fused kernel (used if ws too small) =================
__launch_bounds__(512, 2)
__global__ void swin_fused_kernel(const float* __restrict__ x,
                                  const float* __restrict__ n1w, const float* __restrict__ n1b,
                                  const float* __restrict__ n2w, const float* __restrict__ n2b,
                                  const u16* __restrict__ pkq, const u16* __restrict__ pkp,
                                  const float* __restrict__ projb,
                                  const u16* __restrict__ pk1, const float* __restrict__ f1b,
                                  const u16* __restrict__ pk2, const float* __restrict__ f2b,
                                  float* __restrict__ out)
{
  __shared__ u16 smem[35072];
  u16* Buf1 = smem;
  u16* Buf2 = smem + 16384;
  float* redF   = (float*)(smem + 32768);
  float* statsF = redF + 1024;

  const int tid = threadIdx.x;
  const int w = tid >> 6;
  const int l = tid & 63;
  const int bb = blockIdx.x >> 8;
  const int blkl = blockIdx.x & 255;
  const int l0 = blkl*64 + 4;
  const float* xb = x + (size_t)bb*CL_;
  const int ntb = w*2;

  const int q4 = tid & 15, cg = tid >> 4;
  int lq = l0 + 4*q4; if (lq >= L_) lq -= L_;
  float4 xr[8];
  float s1[4] = {0.f,0.f,0.f,0.f};
  float s2[4] = {0.f,0.f,0.f,0.f};
  #pragma unroll
  for (int ci = 0; ci < 8; ++ci){
    int c = cg*8 + ci;
    float4 d = *(const float4*)(xb + (size_t)c*L_ + lq);
    xr[ci] = d;
    s1[0]+=d.x; s2[0]+=d.x*d.x;  s1[1]+=d.y; s2[1]+=d.y*d.y;
    s1[2]+=d.z; s2[2]+=d.z*d.z;  s1[3]+=d.w; s2[3]+=d.w*d.w;
  }
  #pragma unroll
  for (int off = 16; off < 64; off <<= 1){
    #pragma unroll
    for (int jj = 0; jj < 4; ++jj){
      s1[jj] += __shfl_xor(s1[jj], off);
      s2[jj] += __shfl_xor(s2[jj], off);
    }
  }
  if (l < 16){
    #pragma unroll
    for (int jj = 0; jj < 4; ++jj){
      redF[w*64 + 4*l + jj] = s1[jj];
      redF[512 + w*64 + 4*l + jj] = s2[jj];
    }
  }
  __syncthreads();
  if (tid < 64){
    float a = 0.f, b2 = 0.f;
    #pragma unroll
    for (int ww = 0; ww < 8; ++ww){ a += redF[ww*64 + tid]; b2 += redF[512 + ww*64 + tid]; }
    float mu = a * (1.f/256.f);
    float var = fmaxf(b2 * (1.f/256.f) - mu*mu, 0.f);
    statsF[2*tid] = mu;
    statsF[2*tid+1] = rsqrtf(var + 1e-5f);
  }
  __syncthreads();

  u32 praw[4][4];
  #pragma unroll
  for (int jj = 0; jj < 4; ++jj){
    int t = 4*q4 + jj;
    float mu = statsF[2*t], rs = statsF[2*t+1];
    u32 aw[4];
    #pragma unroll
    for (int cp = 0; cp < 4; ++cp){
      int c0c = cg*8 + 2*cp;
      float v0 = ((const float*)&xr[2*cp])[jj];
      float v1 = ((const float*)&xr[2*cp+1])[jj];
      aw[cp] = pack2((v0-mu)*rs*n1w[c0c] + n1b[c0c], (v1-mu)*rs*n1w[c0c+1] + n1b[c0c+1]);
      praw[jj][cp] = pack2(v0, v1);
    }
    *(uint4*)((char*)Buf1 + t*512 + ((cg*16) ^ ((t&7)<<4))) = make_uint4(aw[0],aw[1],aw[2],aw[3]);
  }
  __syncthreads();

  {
    f32x4 acc[4][2]; ZERO_ACC(acc);
    gemmP(Buf1, pkq + 65536, l, ntb, acc);
    #pragma unroll
    for (int m = 0; m < 4; ++m)
      #pragma unroll
      for (int n2 = 0; n2 < 2; ++n2)
        #pragma unroll
        for (int jj = 0; jj < 4; ++jj){
          int t = m*16 + ((l>>4)<<2) + jj;
          int c = (w<<5) + (n2<<4) + (l&15);
          *(u16*)((char*)Buf2 + t*512 + ((2*c) ^ ((t&7)<<4))) = f2bf(acc[m][n2][jj]);
        }
  }
  __syncthreads();

  const int hh = (tid >> 3) & 7, rr = tid & 7;
  const int tq = w*8 + rr;
  u32 kr[16];
  #pragma unroll
  for (int g = 0; g < 4; ++g){
    uint4 dk = *(const uint4*)((char*)Buf2 + tq*512 + ((hh*64 + 16*g) ^ ((tq&7)<<4)));
    kr[g*4+0] = dk.x; kr[g*4+1] = dk.y; kr[g*4+2] = dk.z; kr[g*4+3] = dk.w;
  }
  __syncthreads();

  {
    f32x4 acc[4][2]; ZERO_ACC(acc);
    gemmP(Buf1, pkq, l, ntb, acc);
    #pragma unroll
    for (int m = 0; m < 4; ++m)
      #pragma unroll
      for (int n2 = 0; n2 < 2; ++n2)
        #pragma unroll
        for (int jj = 0; jj < 4; ++jj){
          int t = m*16 + ((l>>4)<<2) + jj;
          int c = (w<<5) + (n2<<4) + (l&15);
          *(u16*)((char*)Buf2 + t*512 + ((2*c) ^ ((t&7)<<4))) = f2bf(acc[m][n2][jj]);
        }
  }
  __syncthreads();

  float pr[8];
  {
    float qf[32];
    #pragma unroll
    for (int g = 0; g < 4; ++g){
      uint4 dq = *(const uint4*)((char*)Buf2 + tq*512 + ((hh*64 + 16*g) ^ ((tq&7)<<4)));
      qf[g*8+0] = bf2f((u16)dq.x); qf[g*8+1] = bf2f((u16)(dq.x>>16));
      qf[g*8+2] = bf2f((u16)dq.y); qf[g*8+3] = bf2f((u16)(dq.y>>16));
      qf[g*8+4] = bf2f((u16)dq.z); qf[g*8+5] = bf2f((u16)(dq.z>>16));
      qf[g*8+6] = bf2f((u16)dq.w); qf[g*8+7] = bf2f((u16)(dq.w>>16));
    }
    float s[8];
    #pragma unroll
    for (int j = 0; j < 8; ++j){
      float dot = 0.f;
      #pragma unroll
      for (int reg = 0; reg < 16; ++reg){
        u32 kj = (u32)__shfl((int)kr[reg], j, 8);
        dot += qf[2*reg]   * bf2f((u16)kj);
        dot += qf[2*reg+1] * bf2f((u16)(kj>>16));
      }
      s[j] = dot * 0.17677669529663687f;
    }
    float mx = s[0];
    #pragma unroll
    for (int j = 1; j < 8; ++j) mx = fmaxf(mx, s[j]);
    float sum = 0.f;
    #pragma unroll
    for (int j = 0; j < 8; ++j){ pr[j] = __expf(s[j]-mx); sum += pr[j]; }
    float inv = 1.0f / sum;
    #pragma unroll
    for (int j = 0; j < 8; ++j) pr[j] *= inv;
  }
  __syncthreads();

  {
    f32x4 acc[4][2]; ZERO_ACC(acc);
    gemmP(Buf1, pkq + 131072, l, ntb, acc);
    __syncthreads();
    #pragma unroll
    for (int m = 0; m < 4; ++m)
      #pragma unroll
      for (int n2 = 0; n2 < 2; ++n2)
        #pragma unroll
        for (int jj = 0; jj < 4; ++jj){
          int t = m*16 + ((l>>4)<<2) + jj;
          int c = (w<<5) + (n2<<4) + (l&15);
          *(u16*)((char*)Buf2 + t*512 + ((2*c) ^ ((t&7)<<4))) = f2bf(acc[m][n2][jj]);
        }
    #pragma unroll
    for (int jj = 0; jj < 4; ++jj){
      int t = 4*q4 + jj;
      *(uint4*)((char*)Buf1 + t*512 + ((cg*16) ^ ((t&7)<<4))) =
          make_uint4(praw[jj][0], praw[jj][1], praw[jj][2], praw[jj][3]);
    }
  }
  __syncthreads();

  {
    u32 vr[16];
    #pragma unroll
    for (int g = 0; g < 4; ++g){
      uint4 dv = *(const uint4*)((char*)Buf2 + tq*512 + ((hh*64 + 16*g) ^ ((tq&7)<<4)));
      vr[g*4+0] = dv.x; vr[g*4+1] = dv.y; vr[g*4+2] = dv.z; vr[g*4+3] = dv.w;
    }
    float of[32];
    #pragma unroll
    for (int d = 0; d < 32; ++d) of[d] = 0.f;
    #pragma unroll
    for (int j = 0; j < 8; ++j){
      float pj = pr[j];
      #pragma unroll
      for (int reg = 0; reg < 16; ++reg){
        u32 vj = (u32)__shfl((int)vr[reg], j, 8);
        of[2*reg]   += pj*bf2f((u16)vj);
        of[2*reg+1] += pj*bf2f((u16)(vj>>16));
      }
    }
    #pragma unroll
    for (int g = 0; g < 4; ++g){
      uint4 o;
      o.x = pack2(of[g*8+0], of[g*8+1]);
      o.y = pack2(of[g*8+2], of[g*8+3]);
      o.z = pack2(of[g*8+4], of[g*8+5]);
      o.w = pack2(of[g*8+6], of[g*8+7]);
      *(uint4*)((char*)Buf2 + tq*512 + ((hh*64 + 16*g) ^ ((tq&7)<<4))) = o;
    }
  }
  __syncthreads();

  u32 xt1p[4][2][2];
  {
    f32x4 acc[4][2]; ZERO_ACC(acc);
    gemmP(Buf2, pkp, l, ntb, acc);
    __syncthreads();
    #pragma unroll
    for (int m = 0; m < 4; ++m)
      #pragma unroll
      for (int n2 = 0; n2 < 2; ++n2){
        float vv[4];
        #pragma unroll
        for (int jj = 0; jj < 4; ++jj){
          int t = m*16 + ((l>>4)<<2) + jj;
          int c = (w<<5) + (n2<<4) + (l&15);
          float rv = bf2f(*(const u16*)((char*)Buf1 + t*512 + ((2*c) ^ ((t&7)<<4))));
          float v = acc[m][n2][jj] + projb[c] + rv;
          vv[jj] = v;
          *(u16*)((char*)Buf2 + t*512 + 2*c) = f2bf(v);
        }
        xt1p[m][n2][0] = pack2(vv[0], vv[1]);
        xt1p[m][n2][1] = pack2(vv[2], vv[3]);
      }
  }
  __syncthreads();

  {
    float4 wv = *(const float4*)(n2w + 4*l);
    float4 bv = *(const float4*)(n2b + 4*l);
    #pragma unroll 1
    for (int r = 0; r < 8; ++r){
      int t = w*8 + r;
      uint2 d = *(const uint2*)((char*)Buf2 + t*512 + 8*l);
      float f0 = bf2f((u16)d.x), f1 = bf2f((u16)(d.x>>16));
      float f2 = bf2f((u16)d.y), f3 = bf2f((u16)(d.y>>16));
      float ls1 = f0+f1+f2+f3;
      float ls2 = f0*f0+f1*f1+f2*f2+f3*f3;
      #pragma unroll
      for (int off = 1; off < 64; off <<= 1){
        ls1 += __shfl_xor(ls1, off);
        ls2 += __shfl_xor(ls2, off);
      }
      float mu = ls1 * (1.f/256.f);
      float var = fmaxf(ls2 * (1.f/256.f) - mu*mu, 0.f);
      float rs = rsqrtf(var + 1e-5f);
      uint2 pp;
      pp.x = pack2((f0-mu)*rs*wv.x+bv.x, (f1-mu)*rs*wv.y+bv.y);
      pp.y = pack2((f2-mu)*rs*wv.z+bv.z, (f3-mu)*rs*wv.w+bv.w);
      *(uint2*)((char*)Buf1 + t*512 + ((8*l) ^ ((t&7)<<4))) = pp;
    }
  }
  __syncthreads();

  f32x4 acc2[4][2]; ZERO_ACC(acc2);
  #pragma unroll 1
  for (int c2 = 0; c2 < 4; ++c2){
    f32x4 acc1[4][2]; ZERO_ACC(acc1);
    gemmP(Buf1, pk1 + (size_t)c2*65536, l, ntb, acc1);
    __syncthreads();
    #pragma unroll
    for (int m = 0; m < 4; ++m)
      #pragma unroll
      for (int n2 = 0; n2 < 2; ++n2)
        #pragma unroll
        for (int jj = 0; jj < 4; ++jj){
          int t = m*16 + ((l>>4)<<2) + jj;
          int c = (w<<5) + (n2<<4) + (l&15);
          float xv = acc1[m][n2][jj] + f1b[c2*256 + c];
          float g = 0.5f*xv*(1.f + erff(xv*0.70710678118654752f));
          *(u16*)((char*)Buf2 + t*512 + ((2*c) ^ ((t&7)<<4))) = f2bf(g);
        }
    __syncthreads();
    gemmP(Buf2, pk2 + (size_t)c2*65536, l, ntb, acc2);
    __syncthreads();
  }

  float* OutF = (float*)smem;
  #pragma unroll
  for (int m = 0; m < 4; ++m)
    #pragma unroll
    for (int n2 = 0; n2 < 2; ++n2)
      #pragma unroll
      for (int jj = 0; jj < 4; ++jj){
        int t = m*16 + ((l>>4)<<2) + jj;
        int c = (w<<5) + (n2<<4) + (l&15);
        u32 p = xt1p[m][n2][jj>>1];
        float rv = bf2f((u16)((jj&1) ? (p>>16) : (p&0xFFFF)));
        float v = acc2[m][n2][jj] + f2b[c] + rv;
        *(float*)((char*)OutF + c*256 + ((4*t) ^ ((c&15)<<4))) = v;
      }
  __syncthreads();

  float* ob = out + (size_t)bb*CL_;
  #pragma unroll
  for (int ii = 0; ii < 8; ++ii){
    int id = tid + ii*512;
    int c = id >> 4, qd = id & 15;
    int lw = l0 + 4*qd; if (lw >= L_) lw -= L_;
    float4 vv = *(const float4*)((char*)OutF + c*256 + ((16*qd) ^ ((c&15)<<4)));
    *(float4*)(ob + (size_t)c*L_ + lw) = vv;
  }
}

// ---------------- launch ----------------
extern "C" void kernel_launch(void* const* d_in, const int* in_sizes, int n_in,
                              void* d_out, int out_size, void* d_ws, size_t ws_size,
                              hipStream_t stream)
{
  const float* x     = (const float*)d_in[0];
  const float* n1w   = (const float*)d_in[1];
  const float* n1b   = (const float*)d_in[2];
  const float* n2w   = (const float*)d_in[3];
  const float* n2b   = (const float*)d_in[4];
  const float* qkvw  = (const float*)d_in[5];
  const float* projw = (const float*)d_in[6];
  const float* projb = (const float*)d_in[7];
  const float* f1w   = (const float*)d_in[8];
  const float* f1b   = (const float*)d_in[9];
  const float* f2w   = (const float*)d_in[10];
  const float* f2b   = (const float*)d_in[11];
  float* out = (float*)d_out;

  u16* ws  = (u16*)d_ws;
  u16* pkq = ws;                        // 3*65536 u16
  u16* pkp = pkq + 196608;              // 65536
  u16* pk1 = pkp + 65536;               // 4*65536
  u16* pk2 = pk1 + 262144;              // 262144  -> weights total 786432 u16 (1.57 MB)
  u16* xt1g = pk2 + 262144;             // 8*256*16384 u16 = 67.1 MB
  float* statsg = (float*)(xt1g + (size_t)8*CL_);   // 8*16384*2 f32 = 1.05 MB

  size_t need = (size_t)786432*2 + (size_t)8*CL_*2 + (size_t)8*16384*2*4;

  hipLaunchKernelGGL(wpack_kernel, dim3(384), dim3(256), 0, stream,
                     qkvw, projw, f1w, f2w, pkq, pkp, pk1, pk2);
  if (ws_size >= need){
    hipLaunchKernelGGL(swin_attn_kernel, dim3(2048), dim3(512), 0, stream,
                       x, n1w, n1b, pkq, pkp, projb, xt1g, statsg);
    hipLaunchKernelGGL(swin_ff_kernel, dim3(2048), dim3(512), 0, stream,
                       xt1g, statsg, n2w, n2b, pk1, f1b, pk2, f2b, out);
  } else {
    hipLaunchKernelGGL(swin_fused_kernel, dim3(2048), dim3(512), 0, stream,
                       x, n1w, n1b, n2w, n2b, pkq, pkp, projb, pk1, f1b, pk2, f2b, out);
  }
}